// Round 12
// baseline (3117.250 us; speedup 1.0000x reference)
//
#include <hip/hip_runtime.h>
#include <cstdint>
#include <cstddef>

// ---------------------------------------------------------------------------
// Qwen3.5 GatedDeltaNet forward, MI355X (gfx950), f16-MFMA implementation.
// B=2, S=4096, H=2048, HK=16, HV=32, DK=DV=128, KW=4, CS=64.
// R2: phase2 split 4x across DV (grid 64 -> 256), reg-prefetch.
// R3: phase1 register-resident forward substitution.
// R4/R5: 256x256 GEMM (swizzled LDS, XCD swz, GROUP_M=8 map).
// R8: R5 projection arrangement + conv/l2norm fusion + grid-stride smalls.
// R9: GEMM K-loop flattened: 1 K-tile/iter, 2 barriers.
// R10: 1024 threads (16 waves, 4x4 wave-grid, 64x64/wave).
// R11: intra-wave software pipeline — all 16 fragment reads of tile kt issued
//      at the end of iter kt-1; af1/bf1 reads retire under the kc0 MFMA quad
//      (compiler emits counted lgkmcnt). launch_bounds (1024,3) for the +64
//      live fragment VGPRs. Was: per-kc read-burst -> lgkmcnt(0) -> MFMA,
//      block-wide lockstep => LDS unit and MFMA pipe alternated idle.
// ---------------------------------------------------------------------------

typedef _Float16 half_t;
typedef _Float16 half2_t __attribute__((ext_vector_type(2)));
typedef _Float16 half4_t __attribute__((ext_vector_type(4)));
typedef _Float16 half8   __attribute__((ext_vector_type(8)));
typedef float    f32x4   __attribute__((ext_vector_type(4)));

#define MFMA16(a, b, c) __builtin_amdgcn_mfma_f32_16x16x32_f16((a), (b), (c), 0, 0, 0)

#define AS1 __attribute__((address_space(1)))
#define AS3 __attribute__((address_space(3)))

__device__ __forceinline__ void gload16(void* lds, const void* g) {
    __builtin_amdgcn_global_load_lds((AS1 void*)(g), (AS3 void*)(lds), 16, 0, 0);
}

// ---- swizzled-LDS access helpers (XOR byte-bits 4..6 with row&7) ----------
__device__ __forceinline__ void at_wr(float* AT, int i, int j, float v) {
    *(float*)((char*)AT + i * 256 + ((j * 4) ^ ((i & 7) << 4))) = v;
}
__device__ __forceinline__ half8 frag64(const half_t* base, int row, int koff) {
    return *(const half8*)((const char*)base + row * 128 + ((koff * 2) ^ ((row & 7) << 4)));
}
__device__ __forceinline__ void w64(half_t* base, int row, int col, float v) {
    *(half_t*)((char*)base + row * 128 + ((col * 2) ^ ((row & 7) << 4))) = (half_t)v;
}
__device__ __forceinline__ half8 frag128(const half_t* base, int row, int koff) {
    return *(const half8*)((const char*)base + row * 256 + ((koff * 2) ^ ((row & 7) << 4)));
}

// ---------------------------------------------------------------------------
// Cast (grid-stride, 2048 blocks)
// ---------------------------------------------------------------------------
__global__ __launch_bounds__(256) void cast_h_k(const float* __restrict__ src,
                                                half_t* __restrict__ dst) {
    const long n4 = (long)8192 * 2048 / 4;
    for (long i = (long)blockIdx.x * 256 + threadIdx.x; i < n4; i += (long)gridDim.x * 256) {
        f32x4 v = *(const f32x4*)(src + i * 4);
        half4_t h;
        h[0] = (half_t)v[0]; h[1] = (half_t)v[1]; h[2] = (half_t)v[2]; h[3] = (half_t)v[3];
        *(half4_t*)(dst + i * 4) = h;
    }
}

// Column-permuted W1T[n][k], n < 12544:
//   [0,2048) q | [2048,4096) k | [4096,8192) v | [8192,8256) ba |
//   [8256,8448) zero pad | [8448,12544) z
__global__ __launch_bounds__(256) void build_w1t_k(const float* __restrict__ Wq,
                                                   const float* __restrict__ Wba,
                                                   half_t* __restrict__ W1T) {
    __shared__ half_t tile[32][33];
    int n0 = blockIdx.x * 32, k0 = blockIdx.y * 32;
    int tx = threadIdx.x & 31, ty = threadIdx.x >> 5;
#pragma unroll
    for (int t = 0; t < 4; ++t) {
        int k = k0 + ty + t * 8, n = n0 + tx;
        float v = 0.f;
        if (n < 2048) {
            int kh = n >> 7, d = n & 127;
            v = Wq[(long)k * 12288 + kh * 768 + d];
        } else if (n < 4096) {
            int n2 = n - 2048; int kh = n2 >> 7, d = n2 & 127;
            v = Wq[(long)k * 12288 + kh * 768 + 128 + d];
        } else if (n < 8192) {
            int n3 = n - 4096; int vh = n3 >> 7, d = n3 & 127;
            int kh = vh >> 1, jj = vh & 1;
            v = Wq[(long)k * 12288 + kh * 768 + 256 + jj * 128 + d];
        } else if (n < 8256) {
            v = Wba[(long)k * 64 + (n - 8192)];
        } else if (n >= 8448) {
            int n4 = n - 8448; int vh = n4 >> 7, d = n4 & 127;
            int kh = vh >> 1, jj = vh & 1;
            v = Wq[(long)k * 12288 + kh * 768 + 512 + jj * 128 + d];
        }
        tile[ty + t * 8][tx] = (half_t)v;
    }
    __syncthreads();
#pragma unroll
    for (int t = 0; t < 4; ++t) {
        int n = n0 + ty + t * 8, k = k0 + tx;
        W1T[(long)n * 2048 + k] = tile[tx][ty + t * 8];
    }
}

// WoT[n][k] = W_out[k][n]; n < 2048, k < 4096
__global__ __launch_bounds__(256) void build_wot_k(const float* __restrict__ Wo,
                                                   half_t* __restrict__ WoT) {
    __shared__ half_t tile[32][33];
    int n0 = blockIdx.x * 32, k0 = blockIdx.y * 32;
    int tx = threadIdx.x & 31, ty = threadIdx.x >> 5;
#pragma unroll
    for (int t = 0; t < 4; ++t) {
        int k = k0 + ty + t * 8, n = n0 + tx;
        tile[ty + t * 8][tx] = (half_t)Wo[(long)k * 2048 + n];
    }
    __syncthreads();
#pragma unroll
    for (int t = 0; t < 4; ++t) {
        int n = n0 + ty + t * 8, k = k0 + tx;
        WoT[(long)n * 4096 + k] = tile[tx][ty + t * 8];
    }
}

// ---------------------------------------------------------------------------
// 256x256 f16 GEMM: C = A(MxK) * Bt(NxK)^T.  1024 threads (16 waves, 4M x 4N,
// 64x64 out/wave), BK=64, LDS 128 KiB (2 dbuf), GROUP_M=8 + XCD swizzle.
// R11 pipeline per K-tile iter (2 barriers):
//   MFMA kc0 (frags pre-read last iter; af1/bf1 reads retire underneath)
//   MFMA kc1 | BAR | stage(kt+2), vmcnt(4) retires kt+1 | BAR |
//   read all 16 frags of tile kt+1.
// ---------------------------------------------------------------------------
template <int OUT_F16>
__global__ __launch_bounds__(1024, 3) void gemm256_k(const half_t* __restrict__ A,
                                                     const half_t* __restrict__ Bt,
                                                     void* __restrict__ C,
                                                     int K, int ldc,
                                                     int nwgM, int nwgN) {
    __shared__ half_t LA[2][2][8192];   // [buf][half][128 rows x 64 f16]
    __shared__ half_t LB[2][2][8192];
    const int tid = threadIdx.x, lane = tid & 63, w = tid >> 6;   // w 0..15
    const int lo = lane & 15, hi = lane >> 4;
    const int wm = w >> 2, wn = w & 3;
    const int nwg = gridDim.x, q = nwg >> 3, bid = blockIdx.x;
    const int swz = (bid & 7) * q + (bid >> 3);
    const int grp = 8 * nwgN;
    const int gid = swz / grp;
    const int rem = swz - gid * grp;
    const int fm = gid * 8;
    const int gsz = min(nwgM - fm, 8);
    const long tm = fm + rem % gsz;
    const long tn = rem / gsz;
    const long Kb = (long)K * 2;
    const char* Ab = (const char*)A + tm * 256 * Kb;
    const char* Bb = (const char*)Bt + tn * 256 * Kb;
    // staging: wave w writes segs {2w, 2w+1} of 32 x 1KB segs per tile;
    // source column pre-swizzled so swizzled reads see logical data.
    const int scol = ((lane & 7) << 4) ^ ((lane >> 3) << 4);
    const int srow = lane >> 3;
    const int sa0 = w * 2, sa1 = w * 2 + 1;   // seg = h*16 + si

    auto stSeg = [&](half_t (*L)[2][8192], const char* gb0, int kt, int s) {
        int h = s >> 4, si = s & 15;
        gload16((char*)&L[kt & 1][h][0] + si * 1024,
                gb0 + (long)(h * 128 + si * 8 + srow) * Kb + (long)kt * 128 + scol);
    };
    auto stTile = [&](int kt) {
        stSeg(LA, Ab, kt, sa0); stSeg(LA, Ab, kt, sa1);
        stSeg(LB, Bb, kt, sa0); stSeg(LB, Bb, kt, sa1);
    };
    auto rdA = [&](int p, int mt, int kc) -> half8 {
        int r = wm * 64 + mt * 16 + lo;
        int rl = r & 127;
        return *(const half8*)((const char*)&LA[p][r >> 7][0] + rl * 128 +
                               ((kc * 64 + hi * 16) ^ ((rl & 7) << 4)));
    };
    auto rdB = [&](int p, int nt, int kc) -> half8 {
        int r = wn * 64 + nt * 16 + lo;
        int rl = r & 127;
        return *(const half8*)((const char*)&LB[p][r >> 7][0] + rl * 128 +
                               ((kc * 64 + hi * 16) ^ ((rl & 7) << 4)));
    };

    f32x4 acc[4][4] = {};
    half8 af0[4], bf0[4], af1[4], bf1[4];

    auto rdFrags = [&](int p, int kc, half8 (&af)[4], half8 (&bf)[4]) {
#pragma unroll
        for (int mt = 0; mt < 4; ++mt) af[mt] = rdA(p, mt, kc);
#pragma unroll
        for (int nt = 0; nt < 4; ++nt) bf[nt] = rdB(p, nt, kc);
    };
    auto mfmaQ = [&](half8 (&af)[4], half8 (&bf)[4]) {
        __builtin_amdgcn_s_setprio(1);
#pragma unroll
        for (int mt = 0; mt < 4; ++mt)
#pragma unroll
            for (int nt = 0; nt < 4; ++nt)
                acc[mt][nt] = MFMA16(af[mt], bf[nt], acc[mt][nt]);
        __builtin_amdgcn_s_setprio(0);
    };

    const int nkt = K >> 6;
    stTile(0); stTile(1);                                  // 8 outstanding
    asm volatile("s_waitcnt vmcnt(4)" ::: "memory");       // tile 0 landed
    __builtin_amdgcn_s_barrier();
    rdFrags(0, 0, af0, bf0);
    rdFrags(0, 1, af1, bf1);

    for (int kt = 0; kt < nkt; ++kt) {
        const int p = kt & 1;
        mfmaQ(af0, bf0);   // compiler waits only on af0/bf0; af1/bf1 retire here
        mfmaQ(af1, bf1);
        __builtin_amdgcn_s_barrier();      // all buf-p reads done block-wide
        if (kt + 2 < nkt) {
            stTile(kt + 2);                                  // 4 gloads -> buf p
            asm volatile("s_waitcnt vmcnt(4)" ::: "memory"); // kt+1 retired
        } else if (kt + 1 < nkt) {
            asm volatile("s_waitcnt vmcnt(0)" ::: "memory");
        }
        __builtin_amdgcn_s_barrier();      // kt+1 visible block-wide
        if (kt + 1 < nkt) {
            rdFrags(p ^ 1, 0, af0, bf0);
            rdFrags(p ^ 1, 1, af1, bf1);
        }
    }

    const long crow0 = tm * 256 + wm * 64 + hi * 4;
    const long ccol0 = tn * 256 + wn * 64 + lo;
#pragma unroll
    for (int mt = 0; mt < 4; ++mt)
#pragma unroll
        for (int nt = 0; nt < 4; ++nt)
#pragma unroll
            for (int e = 0; e < 4; ++e) {
                long row = crow0 + mt * 16 + e;
                long col = ccol0 + nt * 16;
                if (OUT_F16)
                    ((half_t*)C)[row * (long)ldc + col] = (half_t)acc[mt][nt][e];
                else
                    ((float*)C)[row * (long)ldc + col] = acc[mt][nt][e];
            }
}

// ---------------------------------------------------------------------------
// Causal depthwise conv (KW=4) + SiLU + FUSED l2norm (q,k).  8 ch/thread,
// half8 I/O. mixed rows ldm=8448 (cols 0..8191 live). A head's 128 dims =
// 16 consecutive lanes (8 ch each) of one wave -> 4x shfl_xor reduction.
// grid (4, B*128): bx 0=q, 1=k, 2..3=v; 32-s chunks.
// ---------------------------------------------------------------------------
__global__ __launch_bounds__(256) void conv_silu_k(const half_t* __restrict__ mixedH,
                                                   const float* __restrict__ conv_w,
                                                   half_t* __restrict__ qb,
                                                   half_t* __restrict__ kb,
                                                   half_t* __restrict__ vb) {
    const int ldm = 8448;
    int bx = blockIdx.x;
    int ch0 = (bx * 256 + threadIdx.x) * 8;   // 0..8184
    int b = blockIdx.y >> 7, sc = blockIdx.y & 127;
    int s0 = sc * 32;
    half_t* dptr;
    long dstr;
    float nsc = 1.f;
    bool donorm = (bx < 2);
    if (bx == 0)      { dptr = qb + ch0;          dstr = 2048; nsc = 0.08838834764831845f; }
    else if (bx == 1) { dptr = kb + (ch0 - 2048); dstr = 2048; }
    else              { dptr = vb + (ch0 - 4096); dstr = 4096; }
    float w0[8], w1[8], w2[8], w3[8];
#pragma unroll
    for (int j = 0; j < 8; ++j) {
        f32x4 wv = *(const f32x4*)(conv_w + (ch0 + j) * 4);
        w0[j] = wv[0]; w1[j] = wv[1]; w2[j] = wv[2]; w3[j] = wv[3];
    }
    const half_t* src = mixedH + (long)b * 4096 * ldm + ch0;
    half8 x0 = {}, x1 = {}, x2 = {};
    if (s0 >= 3) {
        x0 = *(const half8*)(src + (long)(s0 - 3) * ldm);
        x1 = *(const half8*)(src + (long)(s0 - 2) * ldm);
        x2 = *(const half8*)(src + (long)(s0 - 1) * ldm);
    }
    for (int s = s0; s < s0 + 32; ++s) {
        half8 x3 = *(const half8*)(src + (long)s * ldm);
        float y[8];
        float ss = 0.f;
#pragma unroll
        for (int j = 0; j < 8; ++j) {
            float t = w0[j] * (float)x0[j] + w1[j] * (float)x1[j] +
                      w2[j] * (float)x2[j] + w3[j] * (float)x3[j];
            t = t / (1.f + __expf(-t));
            y[j] = t;
            ss += t * t;
        }
        half8 yv;
        if (donorm) {
            ss += __shfl_xor(ss, 1);
            ss += __shfl_xor(ss, 2);
            ss += __shfl_xor(ss, 4);
            ss += __shfl_xor(ss, 8);
            float r = rsqrtf(ss + 1e-6f) * nsc;
#pragma unroll
            for (int j = 0; j < 8; ++j) yv[j] = (half_t)(y[j] * r);
        } else {
#pragma unroll
            for (int j = 0; j < 8; ++j) yv[j] = (half_t)y[j];
        }
        *(half8*)(dptr + ((long)b * 4096 + s) * dstr) = yv;
        x0 = x1; x1 = x2; x2 = x3;
    }
}

// ---------------------------------------------------------------------------
// beta = sigmoid(b), g = -exp(A_log)*softplus(a+dt_bias), per-chunk cumsum.
// ba at mixedH cols 8192..8255 (row stride 8448).
// ---------------------------------------------------------------------------
__global__ __launch_bounds__(256) void gate_beta_k(const half_t* __restrict__ mixedH,
                                                   const float* __restrict__ A_log,
                                                   const float* __restrict__ dt_bias,
                                                   float* __restrict__ beta,
                                                   float* __restrict__ gcum) {
    __shared__ float gs[32][64];
    int b = blockIdx.x >> 6, c = blockIdx.x & 63;
    for (int idx = threadIdx.x; idx < 2048; idx += 256) {
        int vh = idx & 31, i = idx >> 5;
        int kh = vh >> 1, j = vh & 1;
        long row = ((long)b * 4096 + c * 64 + i) * 8448 + 8192 + kh * 4;
        float bb = (float)mixedH[row + j];
        float aa = (float)mixedH[row + 2 + j];
        beta[((long)b * 4096 + c * 64 + i) * 32 + vh] = 1.f / (1.f + __expf(-bb));
        float x = aa + dt_bias[vh];
        float sp = (x > 15.f) ? x : log1pf(__expf(x));
        gs[vh][i] = -__expf(A_log[vh]) * sp;
    }
    __syncthreads();
    if (threadIdx.x < 32) {
        int vh = threadIdx.x;
        float cum = 0.f;
        float* gout = gcum + ((long)(b * 32 + vh)) * 4096 + c * 64;
        for (int i = 0; i < 64; ++i) { cum += gs[vh][i]; gout[i] = cum; }
    }
}

// ---------------------------------------------------------------------------
// Phase 1: per (b,vh,chunk): A, T=(I-A)^-1, attn, v_t, -kc.  grid 4096.
// ---------------------------------------------------------------------------
__global__ __launch_bounds__(256) void phase1_k(const half_t* __restrict__ qb,
                                                const half_t* __restrict__ kb,
                                                const half_t* __restrict__ vb,
                                                const float* __restrict__ beta,
                                                const float* __restrict__ gcum,
                                                half_t* __restrict__ attnW,
                                                half_t* __restrict__ vtW,
                                                half_t* __restrict__ kcW) {
    __shared__ float AT[64 * 64];       // swizzled rows (256 B); A f32, then T f16
    __shared__ half_t XT[256 * 64];
    __shared__ float gcS[64], betaS[64], egS[64];
    int blk = blockIdx.x;
    int c = blk & 63, vh = (blk >> 6) & 31, b = blk >> 11;
    int kh = vh >> 1;
    int tid = threadIdx.x, lane = tid & 63, w = tid >> 6, lo = lane & 15, hi = lane >> 4;
    long rowbase = (long)b * 4096 + c * 64;
    if (tid < 64) {
        float g = gcum[((long)(b * 32 + vh)) * 4096 + c * 64 + tid];
        gcS[tid] = g; egS[tid] = __expf(g);
        betaS[tid] = beta[(rowbase + tid) * 32 + vh];
    }
    const half_t* kR = kb + rowbase * 2048 + kh * 128;
    const half_t* qR = qb + rowbase * 2048 + kh * 128;
    f32x4 accG[4] = {}, accA[4] = {};
#pragma unroll
    for (int kt = 0; kt < 4; ++kt) {
        half8 ak = *(const half8*)(kR + (long)(w * 16 + lo) * 2048 + kt * 32 + hi * 8);
        half8 aq = *(const half8*)(qR + (long)(w * 16 + lo) * 2048 + kt * 32 + hi * 8);
#pragma unroll
        for (int n = 0; n < 4; ++n) {
            half8 bk = *(const half8*)(kR + (long)(n * 16 + lo) * 2048 + kt * 32 + hi * 8);
            accG[n] = MFMA16(ak, bk, accG[n]);
            accA[n] = MFMA16(aq, bk, accA[n]);
        }
    }
    __syncthreads();
    half_t* attnB = attnW + (long)blk * 4096;
#pragma unroll
    for (int n = 0; n < 4; ++n)
#pragma unroll
        for (int e = 0; e < 4; ++e) {
            int i = w * 16 + hi * 4 + e;
            int j = n * 16 + lo;
            float dec = (j < i) ? __expf(gcS[i] - gcS[j]) : 0.f;
            float av = (j < i) ? (-betaS[i] * accG[n][e] * dec) : (j == i ? 1.f : 0.f);
            at_wr(AT, i, j, av);
            attnB[(long)i * 64 + j] = (half_t)((j < i) ? accA[n][e] * dec : 0.f);
        }
    __syncthreads();
    if (w == 0) {
        float t[64];
#pragma unroll
        for (int i = 0; i < 64; ++i) t[i] = (lane == i) ? 1.f : 0.f;
#pragma unroll
        for (int i = 1; i < 64; ++i) {
            float a0 = 0.f, a1 = 0.f, a2 = 0.f, a3 = 0.f;
#pragma unroll
            for (int p0 = 0; p0 < i; p0 += 4) {
                f32x4 a4 = *(const f32x4*)((const char*)AT + i * 256 +
                                           ((p0 * 4) ^ ((i & 7) << 4)));
                if (p0 + 0 < i) a0 += a4[0] * t[p0 + 0];
                if (p0 + 1 < i) a1 += a4[1] * t[p0 + 1];
                if (p0 + 2 < i) a2 += a4[2] * t[p0 + 2];
                if (p0 + 3 < i) a3 += a4[3] * t[p0 + 3];
            }
            t[i] += (a0 + a1) + (a2 + a3);
        }
        half_t* TS = (half_t*)AT;
#pragma unroll
        for (int i = 0; i < 64; ++i)
            *(half_t*)((char*)TS + i * 128 + ((lane * 2) ^ ((i & 7) << 4))) = (half_t)t[i];
    } else {
        for (int idx = tid - 64; idx < 4096; idx += 192) {
            int p = idx >> 6, dp = idx & 63;
            float bb = betaS[p], be = betaS[p] * egS[p];
            half2_t vv = *(const half2_t*)(vb + (rowbase + p) * 4096 + vh * 128 + dp * 2);
            half2_t kk = *(const half2_t*)(kb + (rowbase + p) * 2048 + kh * 128 + dp * 2);
            w64(XT, dp * 2,       p, (float)vv[0] * bb);
            w64(XT, dp * 2 + 1,   p, (float)vv[1] * bb);
            w64(XT, 128 + dp * 2,     p, (float)kk[0] * be);
            w64(XT, 128 + dp * 2 + 1, p, (float)kk[1] * be);
        }
    }
    __syncthreads();
    const half_t* TS = (const half_t*)AT;
    f32x4 accO[4][4] = {};
#pragma unroll
    for (int kt = 0; kt < 2; ++kt) {
        half8 tf[4];
#pragma unroll
        for (int m = 0; m < 4; ++m) tf[m] = frag64(TS, m * 16 + lo, kt * 32 + hi * 8);
#pragma unroll
        for (int n = 0; n < 4; ++n) {
            half8 bx = frag64(XT, w * 64 + n * 16 + lo, kt * 32 + hi * 8);
#pragma unroll
            for (int m = 0; m < 4; ++m) accO[m][n] = MFMA16(tf[m], bx, accO[m][n]);
        }
    }
    long ob = (long)blk * 8192;
#pragma unroll
    for (int m = 0; m < 4; ++m)
#pragma unroll
        for (int n = 0; n < 4; ++n)
#pragma unroll
            for (int e = 0; e < 4; ++e) {
                int i = m * 16 + hi * 4 + e;
                int dc = w * 64 + n * 16 + lo;
                float v = accO[m][n][e];
                if (dc < 128) vtW[ob + (long)i * 128 + dc] = (half_t)v;
                else          kcW[ob + (long)i * 128 + dc - 128] = (half_t)(-v);
            }
}

// ---------------------------------------------------------------------------
// Phase 2: sequential chunk scan per (b,vh,DV-slice of 32). grid 256.
// ---------------------------------------------------------------------------
struct P2Ops {
    half8 kcf[4], qf[4], k8[4];
    half8 atf[2];
    half_t vtv[8];
    float gm, gi, g63;
};

__global__ __launch_bounds__(256, 1) void phase2_k(const half_t* __restrict__ qb,
                                                   const half_t* __restrict__ kb,
                                                   const float* __restrict__ gcum,
                                                   const half_t* __restrict__ attnW,
                                                   const half_t* __restrict__ vtW,
                                                   const half_t* __restrict__ kcW,
                                                   half_t* __restrict__ coreH) {
    __shared__ half_t SHs[32 * 128];
    __shared__ half_t vnT[32 * 64];
    __shared__ half_t kdT[128 * 64];
    int blk = blockIdx.x;
    int bvh = blk & 63, js = blk >> 6;
    int vh = bvh & 31, b = bvh >> 5, kh = vh >> 1;
    int j0 = js * 32;
    int tid = threadIdx.x, lane = tid & 63, w = tid >> 6, lo = lane & 15, hi = lane >> 4;
    int ii = tid >> 2, dseg = tid & 3;
    int jm = w >> 1, dql = (w & 1) * 4;
    for (int idx = tid; idx < 32 * 128; idx += 256) SHs[idx] = (half_t)0.f;
    __syncthreads();
    const float* gbase = gcum + (long)bvh * 4096;

    auto loadops = [&](int c, P2Ops& o) {
        long pb = (long)bvh * 64 + c;
        const half_t* kcG = kcW + pb * 8192;
        const half_t* vtG = vtW + pb * 8192;
        const half_t* atG = attnW + pb * 4096;
        long rowbase = (long)b * 4096 + c * 64;
        const float* gp = gbase + c * 64;
#pragma unroll
        for (int kt = 0; kt < 4; ++kt) {
            o.kcf[kt] = *(const half8*)(kcG + (long)(w * 16 + lo) * 128 + kt * 32 + hi * 8);
            o.qf[kt] = *(const half8*)(qb + (rowbase + w * 16 + lo) * 2048 + kh * 128 +
                                       kt * 32 + hi * 8);
        }
#pragma unroll
        for (int kt2 = 0; kt2 < 2; ++kt2)
            o.atf[kt2] = *(const half8*)(atG + (long)(w * 16 + lo) * 64 + kt2 * 32 + hi * 8);
#pragma unroll
        for (int s = 0; s < 4; ++s)
            o.k8[s] = *(const half8*)(kb + (rowbase + ii) * 2048 + kh * 128 + dseg * 32 + s * 8);
#pragma unroll
        for (int n = 0; n < 2; ++n)
#pragma unroll
            for (int e = 0; e < 4; ++e)
                o.vtv[n * 4 + e] = vtG[(long)(w * 16 + hi * 4 + e) * 128 + j0 + n * 16 + lo];
        o.gm = gp[w * 16 + lo];
        o.gi = gp[ii];
        o.g63 = gp[63];
    };

    auto step = [&](int c, P2Ops& o, P2Ops& nx) {
        long rowbase = (long)b * 4096 + c * 64;
        loadops(c + 1 < 64 ? c + 1 : 63, nx);
        half8 bS[4][2];
#pragma unroll
        for (int kt = 0; kt < 4; ++kt) {
            bS[kt][0] = frag128(SHs, lo, kt * 32 + hi * 8);
            bS[kt][1] = frag128(SHs, 16 + lo, kt * 32 + hi * 8);
        }
        f32x4 accV[2];
#pragma unroll
        for (int n = 0; n < 2; ++n)
#pragma unroll
            for (int e = 0; e < 4; ++e) accV[n][e] = (float)o.vtv[n * 4 + e];
#pragma unroll
        for (int kt = 0; kt < 4; ++kt) {
            accV[0] = MFMA16(o.kcf[kt], bS[kt][0], accV[0]);
            accV[1] = MFMA16(o.kcf[kt], bS[kt][1], accV[1]);
        }
#pragma unroll
        for (int n = 0; n < 2; ++n) {
            int j = n * 16 + lo, i0 = w * 16 + hi * 4;
            half4_t h4;
            h4[0] = (half_t)accV[n][0]; h4[1] = (half_t)accV[n][1];
            h4[2] = (half_t)accV[n][2]; h4[3] = (half_t)accV[n][3];
            *(half4_t*)((char*)vnT + j * 128 + ((i0 * 2) ^ ((j & 7) << 4))) = h4;
        }
        {
            float ek = __expf(o.g63 - o.gi);
#pragma unroll
            for (int s = 0; s < 4; ++s)
#pragma unroll
                for (int e2 = 0; e2 < 8; ++e2)
                    w64(kdT, dseg * 32 + s * 8 + e2, ii, (float)o.k8[s][e2] * ek);
        }
        __syncthreads();
        float egm = __expf(o.gm);
        f32x4 accO[2] = {};
#pragma unroll
        for (int kt = 0; kt < 4; ++kt) {
            half8 aq;
#pragma unroll
            for (int e2 = 0; e2 < 8; ++e2) aq[e2] = (half_t)((float)o.qf[kt][e2] * egm);
            accO[0] = MFMA16(aq, bS[kt][0], accO[0]);
            accO[1] = MFMA16(aq, bS[kt][1], accO[1]);
        }
#pragma unroll
        for (int kt2 = 0; kt2 < 2; ++kt2) {
            half8 bV0 = frag64(vnT, lo, kt2 * 32 + hi * 8);
            half8 bV1 = frag64(vnT, 16 + lo, kt2 * 32 + hi * 8);
            accO[0] = MFMA16(o.atf[kt2], bV0, accO[0]);
            accO[1] = MFMA16(o.atf[kt2], bV1, accO[1]);
        }
        f32x4 accU[4] = {};
#pragma unroll
        for (int kt2 = 0; kt2 < 2; ++kt2) {
            half8 avn = frag64(vnT, jm * 16 + lo, kt2 * 32 + hi * 8);
#pragma unroll
            for (int dnn = 0; dnn < 4; ++dnn) {
                half8 bkd = frag64(kdT, (dql + dnn) * 16 + lo, kt2 * 32 + hi * 8);
                accU[dnn] = MFMA16(avn, bkd, accU[dnn]);
            }
        }
#pragma unroll
        for (int n = 0; n < 2; ++n)
#pragma unroll
            for (int e = 0; e < 4; ++e)
                coreH[(rowbase + w * 16 + hi * 4 + e) * 4096 + vh * 128 + j0 + n * 16 + lo] =
                    (half_t)accO[n][e];
        __syncthreads();
        float egl = __expf(o.g63);
#pragma unroll
        for (int dnn = 0; dnn < 4; ++dnn)
#pragma unroll
            for (int e = 0; e < 4; ++e) {
                int j = jm * 16 + hi * 4 + e;
                int d = (dql + dnn) * 16 + lo;
                char* p = (char*)SHs + j * 256 + ((d * 2) ^ ((j & 7) << 4));
                float old = (float)*(half_t*)p;
                *(half_t*)p = (half_t)(old * egl + accU[dnn][e]);
            }
        __syncthreads();
    };

    P2Ops opsA, opsB;
    loadops(0, opsA);
    for (int c = 0; c < 64; c += 2) {
        step(c, opsA, opsB);
        step(c + 1, opsB, opsA);
    }
}

// ---------------------------------------------------------------------------
// Gated RMSNorm + silu(z) gate, IN-PLACE on coreH. One wave per (b,s,vh) row.
// Grid-stride: 4096 blocks x 4 waves x 16 iters = 262144 rows.
// ---------------------------------------------------------------------------
__global__ __launch_bounds__(256) void normgate_k(half_t* __restrict__ coreH,
                                                  const half_t* __restrict__ zH,
                                                  const float* __restrict__ norm_w) {
    int w = threadIdx.x >> 6, lane = threadIdx.x & 63;
    float w0 = norm_w[lane * 2], w1 = norm_w[lane * 2 + 1];
    for (long rid = (long)blockIdx.x * 4 + w; rid < 262144; rid += (long)gridDim.x * 4) {
        long bs = rid >> 5;
        int vh = rid & 31;
        half_t* cr = coreH + bs * 4096 + vh * 128;
        half2_t cv = *(half2_t*)(cr + lane * 2);
        float f0 = (float)cv[0], f1 = (float)cv[1];
        float ss = f0 * f0 + f1 * f1;
#pragma unroll
        for (int off = 32; off; off >>= 1) ss += __shfl_xor(ss, off);
        float rs = rsqrtf(ss * (1.f / 128.f) + 1e-6f);
        half2_t zz = *(const half2_t*)(zH + bs * 4096 + vh * 128 + lane * 2);
        float z0 = (float)zz[0], z1 = (float)zz[1];
        float s0 = z0 / (1.f + __expf(-z0)), s1 = z1 / (1.f + __expf(-z1));
        half2_t o;
        o[0] = (half_t)(f0 * rs * w0 * s0);
        o[1] = (half_t)(f1 * rs * w1 * s1);
        *(half2_t*)(cr + lane * 2) = o;
    }
}

// ---------------------------------------------------------------------------
// Host launcher.  Workspace layout (MiB offsets), hand-aliased, peak 370 MiB:
//   [0,32)    qb      | overlay: hiddenH
//   [32,64)   kb      | overlay: W1T head (W1T = 12544x2048 f16, 49 MiB)
//   [64,128)  vb      | overlay: W1T tail; later coreH
//   [128,129) betaB   [129,130) gcum   [130,146) WoT
//   [146,210) zH
//   [210,342) mixedH (8192 x 8448 f16, 132 MiB) | overlay: attnW [210,242),
//                                                  vtW [242,306), kcW [306,370)
// ---------------------------------------------------------------------------
extern "C" void kernel_launch(void* const* d_in, const int* in_sizes, int n_in,
                              void* d_out, int out_size, void* d_ws, size_t ws_size,
                              hipStream_t stream) {
    const float* hidden  = (const float*)d_in[0];
    const float* W_qkvz  = (const float*)d_in[1];
    const float* W_ba    = (const float*)d_in[2];
    const float* conv_w  = (const float*)d_in[3];
    const float* A_log   = (const float*)d_in[4];
    const float* dt_bias = (const float*)d_in[5];
    const float* norm_w  = (const float*)d_in[6];
    const float* W_out   = (const float*)d_in[7];
    float* out = (float*)d_out;

    char* ws = (char*)d_ws;
    const size_t MB = 1ull << 20;
    half_t* qb      = (half_t*)(ws + 0);
    half_t* kb      = (half_t*)(ws + 32 * MB);
    half_t* vb      = (half_t*)(ws + 64 * MB);
    float*  betaB   = (float*) (ws + 128 * MB);
    float*  gcum    = (float*) (ws + 129 * MB);
    half_t* WoT     = (half_t*)(ws + 130 * MB);
    half_t* zH      = (half_t*)(ws + 146 * MB);
    half_t* mixedH  = (half_t*)(ws + 210 * MB);
    half_t* attnW   = (half_t*)(ws + 210 * MB);
    half_t* vtW     = (half_t*)(ws + 242 * MB);
    half_t* kcW     = (half_t*)(ws + 306 * MB);
    half_t* hiddenH = (half_t*)(ws + 0);
    half_t* W1T     = (half_t*)(ws + 32 * MB);
    half_t* coreH   = (half_t*)(ws + 64 * MB);
    (void)ws_size; (void)in_sizes; (void)n_in; (void)out_size;

    // 1. casts / transposes
    cast_h_k<<<2048, 256, 0, stream>>>(hidden, hiddenH);
    build_w1t_k<<<dim3(392, 64), 256, 0, stream>>>(W_qkvz, W_ba, W1T);
    build_wot_k<<<dim3(64, 128), 256, 0, stream>>>(W_out, WoT);
    // 2. fused projection: qkv+ba (M=8192, N=8448) then z (N=4096); K=2048
    gemm256_k<1><<<1056, 1024, 0, stream>>>(hiddenH, W1T, mixedH, 2048, 8448, 32, 33);
    gemm256_k<1><<<512, 1024, 0, stream>>>(hiddenH, W1T + (size_t)8448 * 2048, zH,
                                           2048, 4096, 32, 16);
    // 3. conv + silu + fused l2norm ; gates
    conv_silu_k<<<dim3(4, 256), 256, 0, stream>>>(mixedH, conv_w, qb, kb, vb);
    gate_beta_k<<<128, 256, 0, stream>>>(mixedH, A_log, dt_bias, betaB, gcum);
    // 4. delta-rule core
    phase1_k<<<4096, 256, 0, stream>>>(qb, kb, vb, betaB, gcum, attnW, vtW, kcW);
    phase2_k<<<256, 256, 0, stream>>>(qb, kb, gcum, attnW, vtW, kcW, coreH);
    // 5. gated RMSNorm (in-place) + output projection (M=8192, N=2048, K=4096)
    normgate_k<<<4096, 256, 0, stream>>>(coreH, zH, norm_w);
    gemm256_k<0><<<256, 1024, 0, stream>>>(coreH, WoT, out, 4096, 2048, 32, 8);
}

// Round 13
// 1109.744 us; speedup vs baseline: 2.8090x; 2.8090x over previous
//
#include <hip/hip_runtime.h>
#include <cstdint>
#include <cstddef>

// ---------------------------------------------------------------------------
// Qwen3.5 GatedDeltaNet forward, MI355X (gfx950), f16-MFMA implementation.
// B=2, S=4096, H=2048, HK=16, HV=32, DK=DV=128, KW=4, CS=64.
// R2: phase2 split 4x across DV (grid 64 -> 256), reg-prefetch.
// R3: phase1 register-resident forward substitution.
// R4/R5: 256x256 GEMM (swizzled LDS, XCD swz, GROUP_M=8 map).
// R8: R5 projection arrangement + conv/l2norm fusion + grid-stride smalls.
// R9: GEMM K-loop flattened: 1 K-tile/iter, 2 barriers.
// R10: 1024 threads (16 waves, 4x4 wave-grid, 64x64/wave) — BEST (1114 us).
// R11 (REVERTED): pre-reading all 16 fragments across the barrier region
//      spilled to scratch (WRITE_SIZE 3.3 GB, MfmaUtil 8%, 2.8x regression).
//      Lesson: cross-barrier live fragment set must stay tiny; R12 is the
//      exact R10 kernel re-established as baseline.
// ---------------------------------------------------------------------------

typedef _Float16 half_t;
typedef _Float16 half2_t __attribute__((ext_vector_type(2)));
typedef _Float16 half4_t __attribute__((ext_vector_type(4)));
typedef _Float16 half8   __attribute__((ext_vector_type(8)));
typedef float    f32x4   __attribute__((ext_vector_type(4)));

#define MFMA16(a, b, c) __builtin_amdgcn_mfma_f32_16x16x32_f16((a), (b), (c), 0, 0, 0)

#define AS1 __attribute__((address_space(1)))
#define AS3 __attribute__((address_space(3)))

__device__ __forceinline__ void gload16(void* lds, const void* g) {
    __builtin_amdgcn_global_load_lds((AS1 void*)(g), (AS3 void*)(lds), 16, 0, 0);
}

// ---- swizzled-LDS access helpers (XOR byte-bits 4..6 with row&7) ----------
__device__ __forceinline__ void at_wr(float* AT, int i, int j, float v) {
    *(float*)((char*)AT + i * 256 + ((j * 4) ^ ((i & 7) << 4))) = v;
}
__device__ __forceinline__ half8 frag64(const half_t* base, int row, int koff) {
    return *(const half8*)((const char*)base + row * 128 + ((koff * 2) ^ ((row & 7) << 4)));
}
__device__ __forceinline__ void w64(half_t* base, int row, int col, float v) {
    *(half_t*)((char*)base + row * 128 + ((col * 2) ^ ((row & 7) << 4))) = (half_t)v;
}
__device__ __forceinline__ half8 frag128(const half_t* base, int row, int koff) {
    return *(const half8*)((const char*)base + row * 256 + ((koff * 2) ^ ((row & 7) << 4)));
}

// ---------------------------------------------------------------------------
// Cast (grid-stride, 2048 blocks)
// ---------------------------------------------------------------------------
__global__ __launch_bounds__(256) void cast_h_k(const float* __restrict__ src,
                                                half_t* __restrict__ dst) {
    const long n4 = (long)8192 * 2048 / 4;
    for (long i = (long)blockIdx.x * 256 + threadIdx.x; i < n4; i += (long)gridDim.x * 256) {
        f32x4 v = *(const f32x4*)(src + i * 4);
        half4_t h;
        h[0] = (half_t)v[0]; h[1] = (half_t)v[1]; h[2] = (half_t)v[2]; h[3] = (half_t)v[3];
        *(half4_t*)(dst + i * 4) = h;
    }
}

// Column-permuted W1T[n][k], n < 12544:
//   [0,2048) q | [2048,4096) k | [4096,8192) v | [8192,8256) ba |
//   [8256,8448) zero pad | [8448,12544) z
__global__ __launch_bounds__(256) void build_w1t_k(const float* __restrict__ Wq,
                                                   const float* __restrict__ Wba,
                                                   half_t* __restrict__ W1T) {
    __shared__ half_t tile[32][33];
    int n0 = blockIdx.x * 32, k0 = blockIdx.y * 32;
    int tx = threadIdx.x & 31, ty = threadIdx.x >> 5;
#pragma unroll
    for (int t = 0; t < 4; ++t) {
        int k = k0 + ty + t * 8, n = n0 + tx;
        float v = 0.f;
        if (n < 2048) {
            int kh = n >> 7, d = n & 127;
            v = Wq[(long)k * 12288 + kh * 768 + d];
        } else if (n < 4096) {
            int n2 = n - 2048; int kh = n2 >> 7, d = n2 & 127;
            v = Wq[(long)k * 12288 + kh * 768 + 128 + d];
        } else if (n < 8192) {
            int n3 = n - 4096; int vh = n3 >> 7, d = n3 & 127;
            int kh = vh >> 1, jj = vh & 1;
            v = Wq[(long)k * 12288 + kh * 768 + 256 + jj * 128 + d];
        } else if (n < 8256) {
            v = Wba[(long)k * 64 + (n - 8192)];
        } else if (n >= 8448) {
            int n4 = n - 8448; int vh = n4 >> 7, d = n4 & 127;
            int kh = vh >> 1, jj = vh & 1;
            v = Wq[(long)k * 12288 + kh * 768 + 512 + jj * 128 + d];
        }
        tile[ty + t * 8][tx] = (half_t)v;
    }
    __syncthreads();
#pragma unroll
    for (int t = 0; t < 4; ++t) {
        int n = n0 + ty + t * 8, k = k0 + tx;
        W1T[(long)n * 2048 + k] = tile[tx][ty + t * 8];
    }
}

// WoT[n][k] = W_out[k][n]; n < 2048, k < 4096
__global__ __launch_bounds__(256) void build_wot_k(const float* __restrict__ Wo,
                                                   half_t* __restrict__ WoT) {
    __shared__ half_t tile[32][33];
    int n0 = blockIdx.x * 32, k0 = blockIdx.y * 32;
    int tx = threadIdx.x & 31, ty = threadIdx.x >> 5;
#pragma unroll
    for (int t = 0; t < 4; ++t) {
        int k = k0 + ty + t * 8, n = n0 + tx;
        tile[ty + t * 8][tx] = (half_t)Wo[(long)k * 2048 + n];
    }
    __syncthreads();
#pragma unroll
    for (int t = 0; t < 4; ++t) {
        int n = n0 + ty + t * 8, k = k0 + tx;
        WoT[(long)n * 4096 + k] = tile[tx][ty + t * 8];
    }
}

// ---------------------------------------------------------------------------
// 256x256 f16 GEMM: C = A(MxK) * Bt(NxK)^T.  1024 threads (16 waves, 4M x 4N,
// 64x64 out/wave), BK=64, LDS 128 KiB (2 dbuf), GROUP_M=8 + XCD swizzle.
// Per K-tile iter (2 barriers):
//   kc0: 8 ds_reads + 16 MFMA | kc1: 8 ds_reads + 16 MFMA
//   BAR | stage(kt+2) (4 gloads/thread) | vmcnt(4) retires kt+1 | BAR
// Invariant entering each iter: 4 loads outstanding (tile kt+1's stages).
// ---------------------------------------------------------------------------
template <int OUT_F16>
__global__ __launch_bounds__(1024, 4) void gemm256_k(const half_t* __restrict__ A,
                                                     const half_t* __restrict__ Bt,
                                                     void* __restrict__ C,
                                                     int K, int ldc,
                                                     int nwgM, int nwgN) {
    __shared__ half_t LA[2][2][8192];   // [buf][half][128 rows x 64 f16]
    __shared__ half_t LB[2][2][8192];
    const int tid = threadIdx.x, lane = tid & 63, w = tid >> 6;   // w 0..15
    const int lo = lane & 15, hi = lane >> 4;
    const int wm = w >> 2, wn = w & 3;
    const int nwg = gridDim.x, q = nwg >> 3, bid = blockIdx.x;
    const int swz = (bid & 7) * q + (bid >> 3);
    const int grp = 8 * nwgN;
    const int gid = swz / grp;
    const int rem = swz - gid * grp;
    const int fm = gid * 8;
    const int gsz = min(nwgM - fm, 8);
    const long tm = fm + rem % gsz;
    const long tn = rem / gsz;
    const long Kb = (long)K * 2;
    const char* Ab = (const char*)A + tm * 256 * Kb;
    const char* Bb = (const char*)Bt + tn * 256 * Kb;
    // staging: wave w writes segs {2w, 2w+1} of 32 x 1KB segs per tile;
    // source column pre-swizzled so swizzled reads see logical data.
    const int scol = ((lane & 7) << 4) ^ ((lane >> 3) << 4);
    const int srow = lane >> 3;
    const int sa0 = w * 2, sa1 = w * 2 + 1;   // seg = h*16 + si

    auto stSeg = [&](half_t (*L)[2][8192], const char* gb0, int kt, int s) {
        int h = s >> 4, si = s & 15;
        gload16((char*)&L[kt & 1][h][0] + si * 1024,
                gb0 + (long)(h * 128 + si * 8 + srow) * Kb + (long)kt * 128 + scol);
    };
    auto stTile = [&](int kt) {
        stSeg(LA, Ab, kt, sa0); stSeg(LA, Ab, kt, sa1);
        stSeg(LB, Bb, kt, sa0); stSeg(LB, Bb, kt, sa1);
    };
    auto rdA = [&](int p, int mt, int kc) -> half8 {
        int r = wm * 64 + mt * 16 + lo;
        int rl = r & 127;
        return *(const half8*)((const char*)&LA[p][r >> 7][0] + rl * 128 +
                               ((kc * 64 + hi * 16) ^ ((rl & 7) << 4)));
    };
    auto rdB = [&](int p, int nt, int kc) -> half8 {
        int r = wn * 64 + nt * 16 + lo;
        int rl = r & 127;
        return *(const half8*)((const char*)&LB[p][r >> 7][0] + rl * 128 +
                               ((kc * 64 + hi * 16) ^ ((rl & 7) << 4)));
    };

    f32x4 acc[4][4] = {};

    const int nkt = K >> 6;
    stTile(0); stTile(1);                                  // 8 outstanding
    asm volatile("s_waitcnt vmcnt(4)" ::: "memory");       // tile 0 landed
    __builtin_amdgcn_s_barrier();

    for (int kt = 0; kt < nkt; ++kt) {
        const int p = kt & 1;
#pragma unroll
        for (int kc = 0; kc < 2; ++kc) {
            half8 af[4], bf[4];
#pragma unroll
            for (int mt = 0; mt < 4; ++mt) af[mt] = rdA(p, mt, kc);
#pragma unroll
            for (int nt = 0; nt < 4; ++nt) bf[nt] = rdB(p, nt, kc);
            __builtin_amdgcn_s_setprio(1);
#pragma unroll
            for (int mt = 0; mt < 4; ++mt)
#pragma unroll
                for (int nt = 0; nt < 4; ++nt)
                    acc[mt][nt] = MFMA16(af[mt], bf[nt], acc[mt][nt]);
            __builtin_amdgcn_s_setprio(0);
        }
        __builtin_amdgcn_s_barrier();      // all buf-p reads done block-wide
        if (kt + 2 < nkt) {
            stTile(kt + 2);                                  // 4 gloads -> buf p
            asm volatile("s_waitcnt vmcnt(4)" ::: "memory"); // kt+1 retired
        } else if (kt + 1 < nkt) {
            asm volatile("s_waitcnt vmcnt(0)" ::: "memory");
        }
        __builtin_amdgcn_s_barrier();      // kt+1 visible block-wide
    }

    const long crow0 = tm * 256 + wm * 64 + hi * 4;
    const long ccol0 = tn * 256 + wn * 64 + lo;
#pragma unroll
    for (int mt = 0; mt < 4; ++mt)
#pragma unroll
        for (int nt = 0; nt < 4; ++nt)
#pragma unroll
            for (int e = 0; e < 4; ++e) {
                long row = crow0 + mt * 16 + e;
                long col = ccol0 + nt * 16;
                if (OUT_F16)
                    ((half_t*)C)[row * (long)ldc + col] = (half_t)acc[mt][nt][e];
                else
                    ((float*)C)[row * (long)ldc + col] = acc[mt][nt][e];
            }
}

// ---------------------------------------------------------------------------
// Causal depthwise conv (KW=4) + SiLU + FUSED l2norm (q,k).  8 ch/thread,
// half8 I/O. mixed rows ldm=8448 (cols 0..8191 live). A head's 128 dims =
// 16 consecutive lanes (8 ch each) of one wave -> 4x shfl_xor reduction.
// grid (4, B*128): bx 0=q, 1=k, 2..3=v; 32-s chunks.
// ---------------------------------------------------------------------------
__global__ __launch_bounds__(256) void conv_silu_k(const half_t* __restrict__ mixedH,
                                                   const float* __restrict__ conv_w,
                                                   half_t* __restrict__ qb,
                                                   half_t* __restrict__ kb,
                                                   half_t* __restrict__ vb) {
    const int ldm = 8448;
    int bx = blockIdx.x;
    int ch0 = (bx * 256 + threadIdx.x) * 8;   // 0..8184
    int b = blockIdx.y >> 7, sc = blockIdx.y & 127;
    int s0 = sc * 32;
    half_t* dptr;
    long dstr;
    float nsc = 1.f;
    bool donorm = (bx < 2);
    if (bx == 0)      { dptr = qb + ch0;          dstr = 2048; nsc = 0.08838834764831845f; }
    else if (bx == 1) { dptr = kb + (ch0 - 2048); dstr = 2048; }
    else              { dptr = vb + (ch0 - 4096); dstr = 4096; }
    float w0[8], w1[8], w2[8], w3[8];
#pragma unroll
    for (int j = 0; j < 8; ++j) {
        f32x4 wv = *(const f32x4*)(conv_w + (ch0 + j) * 4);
        w0[j] = wv[0]; w1[j] = wv[1]; w2[j] = wv[2]; w3[j] = wv[3];
    }
    const half_t* src = mixedH + (long)b * 4096 * ldm + ch0;
    half8 x0 = {}, x1 = {}, x2 = {};
    if (s0 >= 3) {
        x0 = *(const half8*)(src + (long)(s0 - 3) * ldm);
        x1 = *(const half8*)(src + (long)(s0 - 2) * ldm);
        x2 = *(const half8*)(src + (long)(s0 - 1) * ldm);
    }
    for (int s = s0; s < s0 + 32; ++s) {
        half8 x3 = *(const half8*)(src + (long)s * ldm);
        float y[8];
        float ss = 0.f;
#pragma unroll
        for (int j = 0; j < 8; ++j) {
            float t = w0[j] * (float)x0[j] + w1[j] * (float)x1[j] +
                      w2[j] * (float)x2[j] + w3[j] * (float)x3[j];
            t = t / (1.f + __expf(-t));
            y[j] = t;
            ss += t * t;
        }
        half8 yv;
        if (donorm) {
            ss += __shfl_xor(ss, 1);
            ss += __shfl_xor(ss, 2);
            ss += __shfl_xor(ss, 4);
            ss += __shfl_xor(ss, 8);
            float r = rsqrtf(ss + 1e-6f) * nsc;
#pragma unroll
            for (int j = 0; j < 8; ++j) yv[j] = (half_t)(y[j] * r);
        } else {
#pragma unroll
            for (int j = 0; j < 8; ++j) yv[j] = (half_t)y[j];
        }
        *(half8*)(dptr + ((long)b * 4096 + s) * dstr) = yv;
        x0 = x1; x1 = x2; x2 = x3;
    }
}

// ---------------------------------------------------------------------------
// beta = sigmoid(b), g = -exp(A_log)*softplus(a+dt_bias), per-chunk cumsum.
// ba at mixedH cols 8192..8255 (row stride 8448).
// ---------------------------------------------------------------------------
__global__ __launch_bounds__(256) void gate_beta_k(const half_t* __restrict__ mixedH,
                                                   const float* __restrict__ A_log,
                                                   const float* __restrict__ dt_bias,
                                                   float* __restrict__ beta,
                                                   float* __restrict__ gcum) {
    __shared__ float gs[32][64];
    int b = blockIdx.x >> 6, c = blockIdx.x & 63;
    for (int idx = threadIdx.x; idx < 2048; idx += 256) {
        int vh = idx & 31, i = idx >> 5;
        int kh = vh >> 1, j = vh & 1;
        long row = ((long)b * 4096 + c * 64 + i) * 8448 + 8192 + kh * 4;
        float bb = (float)mixedH[row + j];
        float aa = (float)mixedH[row + 2 + j];
        beta[((long)b * 4096 + c * 64 + i) * 32 + vh] = 1.f / (1.f + __expf(-bb));
        float x = aa + dt_bias[vh];
        float sp = (x > 15.f) ? x : log1pf(__expf(x));
        gs[vh][i] = -__expf(A_log[vh]) * sp;
    }
    __syncthreads();
    if (threadIdx.x < 32) {
        int vh = threadIdx.x;
        float cum = 0.f;
        float* gout = gcum + ((long)(b * 32 + vh)) * 4096 + c * 64;
        for (int i = 0; i < 64; ++i) { cum += gs[vh][i]; gout[i] = cum; }
    }
}

// ---------------------------------------------------------------------------
// Phase 1: per (b,vh,chunk): A, T=(I-A)^-1, attn, v_t, -kc.  grid 4096.
// ---------------------------------------------------------------------------
__global__ __launch_bounds__(256) void phase1_k(const half_t* __restrict__ qb,
                                                const half_t* __restrict__ kb,
                                                const half_t* __restrict__ vb,
                                                const float* __restrict__ beta,
                                                const float* __restrict__ gcum,
                                                half_t* __restrict__ attnW,
                                                half_t* __restrict__ vtW,
                                                half_t* __restrict__ kcW) {
    __shared__ float AT[64 * 64];       // swizzled rows (256 B); A f32, then T f16
    __shared__ half_t XT[256 * 64];
    __shared__ float gcS[64], betaS[64], egS[64];
    int blk = blockIdx.x;
    int c = blk & 63, vh = (blk >> 6) & 31, b = blk >> 11;
    int kh = vh >> 1;
    int tid = threadIdx.x, lane = tid & 63, w = tid >> 6, lo = lane & 15, hi = lane >> 4;
    long rowbase = (long)b * 4096 + c * 64;
    if (tid < 64) {
        float g = gcum[((long)(b * 32 + vh)) * 4096 + c * 64 + tid];
        gcS[tid] = g; egS[tid] = __expf(g);
        betaS[tid] = beta[(rowbase + tid) * 32 + vh];
    }
    const half_t* kR = kb + rowbase * 2048 + kh * 128;
    const half_t* qR = qb + rowbase * 2048 + kh * 128;
    f32x4 accG[4] = {}, accA[4] = {};
#pragma unroll
    for (int kt = 0; kt < 4; ++kt) {
        half8 ak = *(const half8*)(kR + (long)(w * 16 + lo) * 2048 + kt * 32 + hi * 8);
        half8 aq = *(const half8*)(qR + (long)(w * 16 + lo) * 2048 + kt * 32 + hi * 8);
#pragma unroll
        for (int n = 0; n < 4; ++n) {
            half8 bk = *(const half8*)(kR + (long)(n * 16 + lo) * 2048 + kt * 32 + hi * 8);
            accG[n] = MFMA16(ak, bk, accG[n]);
            accA[n] = MFMA16(aq, bk, accA[n]);
        }
    }
    __syncthreads();
    half_t* attnB = attnW + (long)blk * 4096;
#pragma unroll
    for (int n = 0; n < 4; ++n)
#pragma unroll
        for (int e = 0; e < 4; ++e) {
            int i = w * 16 + hi * 4 + e;
            int j = n * 16 + lo;
            float dec = (j < i) ? __expf(gcS[i] - gcS[j]) : 0.f;
            float av = (j < i) ? (-betaS[i] * accG[n][e] * dec) : (j == i ? 1.f : 0.f);
            at_wr(AT, i, j, av);
            attnB[(long)i * 64 + j] = (half_t)((j < i) ? accA[n][e] * dec : 0.f);
        }
    __syncthreads();
    if (w == 0) {
        float t[64];
#pragma unroll
        for (int i = 0; i < 64; ++i) t[i] = (lane == i) ? 1.f : 0.f;
#pragma unroll
        for (int i = 1; i < 64; ++i) {
            float a0 = 0.f, a1 = 0.f, a2 = 0.f, a3 = 0.f;
#pragma unroll
            for (int p0 = 0; p0 < i; p0 += 4) {
                f32x4 a4 = *(const f32x4*)((const char*)AT + i * 256 +
                                           ((p0 * 4) ^ ((i & 7) << 4)));
                if (p0 + 0 < i) a0 += a4[0] * t[p0 + 0];
                if (p0 + 1 < i) a1 += a4[1] * t[p0 + 1];
                if (p0 + 2 < i) a2 += a4[2] * t[p0 + 2];
                if (p0 + 3 < i) a3 += a4[3] * t[p0 + 3];
            }
            t[i] += (a0 + a1) + (a2 + a3);
        }
        half_t* TS = (half_t*)AT;
#pragma unroll
        for (int i = 0; i < 64; ++i)
            *(half_t*)((char*)TS + i * 128 + ((lane * 2) ^ ((i & 7) << 4))) = (half_t)t[i];
    } else {
        for (int idx = tid - 64; idx < 4096; idx += 192) {
            int p = idx >> 6, dp = idx & 63;
            float bb = betaS[p], be = betaS[p] * egS[p];
            half2_t vv = *(const half2_t*)(vb + (rowbase + p) * 4096 + vh * 128 + dp * 2);
            half2_t kk = *(const half2_t*)(kb + (rowbase + p) * 2048 + kh * 128 + dp * 2);
            w64(XT, dp * 2,       p, (float)vv[0] * bb);
            w64(XT, dp * 2 + 1,   p, (float)vv[1] * bb);
            w64(XT, 128 + dp * 2,     p, (float)kk[0] * be);
            w64(XT, 128 + dp * 2 + 1, p, (float)kk[1] * be);
        }
    }
    __syncthreads();
    const half_t* TS = (const half_t*)AT;
    f32x4 accO[4][4] = {};
#pragma unroll
    for (int kt = 0; kt < 2; ++kt) {
        half8 tf[4];
#pragma unroll
        for (int m = 0; m < 4; ++m) tf[m] = frag64(TS, m * 16 + lo, kt * 32 + hi * 8);
#pragma unroll
        for (int n = 0; n < 4; ++n) {
            half8 bx = frag64(XT, w * 64 + n * 16 + lo, kt * 32 + hi * 8);
#pragma unroll
            for (int m = 0; m < 4; ++m) accO[m][n] = MFMA16(tf[m], bx, accO[m][n]);
        }
    }
    long ob = (long)blk * 8192;
#pragma unroll
    for (int m = 0; m < 4; ++m)
#pragma unroll
        for (int n = 0; n < 4; ++n)
#pragma unroll
            for (int e = 0; e < 4; ++e) {
                int i = m * 16 + hi * 4 + e;
                int dc = w * 64 + n * 16 + lo;
                float v = accO[m][n][e];
                if (dc < 128) vtW[ob + (long)i * 128 + dc] = (half_t)v;
                else          kcW[ob + (long)i * 128 + dc - 128] = (half_t)(-v);
            }
}

// ---------------------------------------------------------------------------
// Phase 2: sequential chunk scan per (b,vh,DV-slice of 32). grid 256.
// ---------------------------------------------------------------------------
struct P2Ops {
    half8 kcf[4], qf[4], k8[4];
    half8 atf[2];
    half_t vtv[8];
    float gm, gi, g63;
};

__global__ __launch_bounds__(256, 1) void phase2_k(const half_t* __restrict__ qb,
                                                   const half_t* __restrict__ kb,
                                                   const float* __restrict__ gcum,
                                                   const half_t* __restrict__ attnW,
                                                   const half_t* __restrict__ vtW,
                                                   const half_t* __restrict__ kcW,
                                                   half_t* __restrict__ coreH) {
    __shared__ half_t SHs[32 * 128];
    __shared__ half_t vnT[32 * 64];
    __shared__ half_t kdT[128 * 64];
    int blk = blockIdx.x;
    int bvh = blk & 63, js = blk >> 6;
    int vh = bvh & 31, b = bvh >> 5, kh = vh >> 1;
    int j0 = js * 32;
    int tid = threadIdx.x, lane = tid & 63, w = tid >> 6, lo = lane & 15, hi = lane >> 4;
    int ii = tid >> 2, dseg = tid & 3;
    int jm = w >> 1, dql = (w & 1) * 4;
    for (int idx = tid; idx < 32 * 128; idx += 256) SHs[idx] = (half_t)0.f;
    __syncthreads();
    const float* gbase = gcum + (long)bvh * 4096;

    auto loadops = [&](int c, P2Ops& o) {
        long pb = (long)bvh * 64 + c;
        const half_t* kcG = kcW + pb * 8192;
        const half_t* vtG = vtW + pb * 8192;
        const half_t* atG = attnW + pb * 4096;
        long rowbase = (long)b * 4096 + c * 64;
        const float* gp = gbase + c * 64;
#pragma unroll
        for (int kt = 0; kt < 4; ++kt) {
            o.kcf[kt] = *(const half8*)(kcG + (long)(w * 16 + lo) * 128 + kt * 32 + hi * 8);
            o.qf[kt] = *(const half8*)(qb + (rowbase + w * 16 + lo) * 2048 + kh * 128 +
                                       kt * 32 + hi * 8);
        }
#pragma unroll
        for (int kt2 = 0; kt2 < 2; ++kt2)
            o.atf[kt2] = *(const half8*)(atG + (long)(w * 16 + lo) * 64 + kt2 * 32 + hi * 8);
#pragma unroll
        for (int s = 0; s < 4; ++s)
            o.k8[s] = *(const half8*)(kb + (rowbase + ii) * 2048 + kh * 128 + dseg * 32 + s * 8);
#pragma unroll
        for (int n = 0; n < 2; ++n)
#pragma unroll
            for (int e = 0; e < 4; ++e)
                o.vtv[n * 4 + e] = vtG[(long)(w * 16 + hi * 4 + e) * 128 + j0 + n * 16 + lo];
        o.gm = gp[w * 16 + lo];
        o.gi = gp[ii];
        o.g63 = gp[63];
    };

    auto step = [&](int c, P2Ops& o, P2Ops& nx) {
        long rowbase = (long)b * 4096 + c * 64;
        loadops(c + 1 < 64 ? c + 1 : 63, nx);
        half8 bS[4][2];
#pragma unroll
        for (int kt = 0; kt < 4; ++kt) {
            bS[kt][0] = frag128(SHs, lo, kt * 32 + hi * 8);
            bS[kt][1] = frag128(SHs, 16 + lo, kt * 32 + hi * 8);
        }
        f32x4 accV[2];
#pragma unroll
        for (int n = 0; n < 2; ++n)
#pragma unroll
            for (int e = 0; e < 4; ++e) accV[n][e] = (float)o.vtv[n * 4 + e];
#pragma unroll
        for (int kt = 0; kt < 4; ++kt) {
            accV[0] = MFMA16(o.kcf[kt], bS[kt][0], accV[0]);
            accV[1] = MFMA16(o.kcf[kt], bS[kt][1], accV[1]);
        }
#pragma unroll
        for (int n = 0; n < 2; ++n) {
            int j = n * 16 + lo, i0 = w * 16 + hi * 4;
            half4_t h4;
            h4[0] = (half_t)accV[n][0]; h4[1] = (half_t)accV[n][1];
            h4[2] = (half_t)accV[n][2]; h4[3] = (half_t)accV[n][3];
            *(half4_t*)((char*)vnT + j * 128 + ((i0 * 2) ^ ((j & 7) << 4))) = h4;
        }
        {
            float ek = __expf(o.g63 - o.gi);
#pragma unroll
            for (int s = 0; s < 4; ++s)
#pragma unroll
                for (int e2 = 0; e2 < 8; ++e2)
                    w64(kdT, dseg * 32 + s * 8 + e2, ii, (float)o.k8[s][e2] * ek);
        }
        __syncthreads();
        float egm = __expf(o.gm);
        f32x4 accO[2] = {};
#pragma unroll
        for (int kt = 0; kt < 4; ++kt) {
            half8 aq;
#pragma unroll
            for (int e2 = 0; e2 < 8; ++e2) aq[e2] = (half_t)((float)o.qf[kt][e2] * egm);
            accO[0] = MFMA16(aq, bS[kt][0], accO[0]);
            accO[1] = MFMA16(aq, bS[kt][1], accO[1]);
        }
#pragma unroll
        for (int kt2 = 0; kt2 < 2; ++kt2) {
            half8 bV0 = frag64(vnT, lo, kt2 * 32 + hi * 8);
            half8 bV1 = frag64(vnT, 16 + lo, kt2 * 32 + hi * 8);
            accO[0] = MFMA16(o.atf[kt2], bV0, accO[0]);
            accO[1] = MFMA16(o.atf[kt2], bV1, accO[1]);
        }
        f32x4 accU[4] = {};
#pragma unroll
        for (int kt2 = 0; kt2 < 2; ++kt2) {
            half8 avn = frag64(vnT, jm * 16 + lo, kt2 * 32 + hi * 8);
#pragma unroll
            for (int dnn = 0; dnn < 4; ++dnn) {
                half8 bkd = frag64(kdT, (dql + dnn) * 16 + lo, kt2 * 32 + hi * 8);
                accU[dnn] = MFMA16(avn, bkd, accU[dnn]);
            }
        }
#pragma unroll
        for (int n = 0; n < 2; ++n)
#pragma unroll
            for (int e = 0; e < 4; ++e)
                coreH[(rowbase + w * 16 + hi * 4 + e) * 4096 + vh * 128 + j0 + n * 16 + lo] =
                    (half_t)accO[n][e];
        __syncthreads();
        float egl = __expf(o.g63);
#pragma unroll
        for (int dnn = 0; dnn < 4; ++dnn)
#pragma unroll
            for (int e = 0; e < 4; ++e) {
                int j = jm * 16 + hi * 4 + e;
                int d = (dql + dnn) * 16 + lo;
                char* p = (char*)SHs + j * 256 + ((d * 2) ^ ((j & 7) << 4));
                float old = (float)*(half_t*)p;
                *(half_t*)p = (half_t)(old * egl + accU[dnn][e]);
            }
        __syncthreads();
    };

    P2Ops opsA, opsB;
    loadops(0, opsA);
    for (int c = 0; c < 64; c += 2) {
        step(c, opsA, opsB);
        step(c + 1, opsB, opsA);
    }
}

// ---------------------------------------------------------------------------
// Gated RMSNorm + silu(z) gate, IN-PLACE on coreH. One wave per (b,s,vh) row.
// Grid-stride: 4096 blocks x 4 waves x 16 iters = 262144 rows.
// ---------------------------------------------------------------------------
__global__ __launch_bounds__(256) void normgate_k(half_t* __restrict__ coreH,
                                                  const half_t* __restrict__ zH,
                                                  const float* __restrict__ norm_w) {
    int w = threadIdx.x >> 6, lane = threadIdx.x & 63;
    float w0 = norm_w[lane * 2], w1 = norm_w[lane * 2 + 1];
    for (long rid = (long)blockIdx.x * 4 + w; rid < 262144; rid += (long)gridDim.x * 4) {
        long bs = rid >> 5;
        int vh = rid & 31;
        half_t* cr = coreH + bs * 4096 + vh * 128;
        half2_t cv = *(half2_t*)(cr + lane * 2);
        float f0 = (float)cv[0], f1 = (float)cv[1];
        float ss = f0 * f0 + f1 * f1;
#pragma unroll
        for (int off = 32; off; off >>= 1) ss += __shfl_xor(ss, off);
        float rs = rsqrtf(ss * (1.f / 128.f) + 1e-6f);
        half2_t zz = *(const half2_t*)(zH + bs * 4096 + vh * 128 + lane * 2);
        float z0 = (float)zz[0], z1 = (float)zz[1];
        float s0 = z0 / (1.f + __expf(-z0)), s1 = z1 / (1.f + __expf(-z1));
        half2_t o;
        o[0] = (half_t)(f0 * rs * w0 * s0);
        o[1] = (half_t)(f1 * rs * w1 * s1);
        *(half2_t*)(cr + lane * 2) = o;
    }
}

// ---------------------------------------------------------------------------
// Host launcher.  Workspace layout (MiB offsets), hand-aliased, peak 370 MiB:
//   [0,32)    qb      | overlay: hiddenH
//   [32,64)   kb      | overlay: W1T head (W1T = 12544x2048 f16, 49 MiB)
//   [64,128)  vb      | overlay: W1T tail; later coreH
//   [128,129) betaB   [129,130) gcum   [130,146) WoT
//   [146,210) zH
//   [210,342) mixedH (8192 x 8448 f16, 132 MiB) | overlay: attnW [210,242),
//                                                  vtW [242,306), kcW [306,370)
// ---------------------------------------------------------------------------
extern "C" void kernel_launch(void* const* d_in, const int* in_sizes, int n_in,
                              void* d_out, int out_size, void* d_ws, size_t ws_size,
                              hipStream_t stream) {
    const float* hidden  = (const float*)d_in[0];
    const float* W_qkvz  = (const float*)d_in[1];
    const float* W_ba    = (const float*)d_in[2];
    const float* conv_w  = (const float*)d_in[3];
    const float* A_log   = (const float*)d_in[4];
    const float* dt_bias = (const float*)d_in[5];
    const float* norm_w  = (const float*)d_in[6];
    const float* W_out   = (const float*)d_in[7];
    float* out = (float*)d_out;

    char* ws = (char*)d_ws;
    const size_t MB = 1ull << 20;
    half_t* qb      = (half_t*)(ws + 0);
    half_t* kb      = (half_t*)(ws + 32 * MB);
    half_t* vb      = (half_t*)(ws + 64 * MB);
    float*  betaB   = (float*) (ws + 128 * MB);
    float*  gcum    = (float*) (ws + 129 * MB);
    half_t* WoT     = (half_t*)(ws + 130 * MB);
    half_t* zH      = (half_t*)(ws + 146 * MB);
    half_t* mixedH  = (half_t*)(ws + 210 * MB);
    half_t* attnW   = (half_t*)(ws + 210 * MB);
    half_t* vtW     = (half_t*)(ws + 242 * MB);
    half_t* kcW     = (half_t*)(ws + 306 * MB);
    half_t* hiddenH = (half_t*)(ws + 0);
    half_t* W1T     = (half_t*)(ws + 32 * MB);
    half_t* coreH   = (half_t*)(ws + 64 * MB);
    (void)ws_size; (void)in_sizes; (void)n_in; (void)out_size;

    // 1. casts / transposes
    cast_h_k<<<2048, 256, 0, stream>>>(hidden, hiddenH);
    build_w1t_k<<<dim3(392, 64), 256, 0, stream>>>(W_qkvz, W_ba, W1T);
    build_wot_k<<<dim3(64, 128), 256, 0, stream>>>(W_out, WoT);
    // 2. fused projection: qkv+ba (M=8192, N=8448) then z (N=4096); K=2048
    gemm256_k<1><<<1056, 1024, 0, stream>>>(hiddenH, W1T, mixedH, 2048, 8448, 32, 33);
    gemm256_k<1><<<512, 1024, 0, stream>>>(hiddenH, W1T + (size_t)8448 * 2048, zH,
                                           2048, 4096, 32, 16);
    // 3. conv + silu + fused l2norm ; gates
    conv_silu_k<<<dim3(4, 256), 256, 0, stream>>>(mixedH, conv_w, qb, kb, vb);
    gate_beta_k<<<128, 256, 0, stream>>>(mixedH, A_log, dt_bias, betaB, gcum);
    // 4. delta-rule core
    phase1_k<<<4096, 256, 0, stream>>>(qb, kb, vb, betaB, gcum, attnW, vtW, kcW);
    phase2_k<<<256, 256, 0, stream>>>(qb, kb, gcum, attnW, vtW, kcW, coreH);
    // 5. gated RMSNorm (in-place) + output projection (M=8192, N=2048, K=4096)
    normgate_k<<<4096, 256, 0, stream>>>(coreH, zH, norm_w);
    gemm256_k<0><<<256, 1024, 0, stream>>>(coreH, WoT, out, 4096, 2048, 32, 8);
}

// Round 14
// 1090.884 us; speedup vs baseline: 2.8575x; 1.0173x over previous
//
#include <hip/hip_runtime.h>
#include <cstdint>
#include <cstddef>

// ---------------------------------------------------------------------------
// Qwen3.5 GatedDeltaNet forward, MI355X (gfx950), f16-MFMA implementation.
// B=2, S=4096, H=2048, HK=16, HV=32, DK=DV=128, KW=4, CS=64.
// R2: phase2 split 4x across DV (grid 64 -> 256), reg-prefetch.
// R3: phase1 register-resident forward substitution.
// R4/R5: 256x256 GEMM (swizzled LDS, XCD swz, GROUP_M=8 map).
// R8: R5 projection arrangement + conv/l2norm fusion + grid-stride smalls.
// R9: GEMM K-loop flattened: 1 K-tile/iter, 2 barriers.
// R10/R12: 1024 threads (16 waves, 4x4 wave-grid, 64x64/wave) — 1110 us.
// R13: gemm1a+gemm1b merged into ONE dispatch (1568 blocks; W1T contiguous
//      across the qkvba|z split, C-write branches on block-uniform tn) —
//      kills one partial-round tail + A-panel L2 reuse. setprio removed
//      (m190: null/negative on lockstep GEMM structures).
// ---------------------------------------------------------------------------

typedef _Float16 half_t;
typedef _Float16 half2_t __attribute__((ext_vector_type(2)));
typedef _Float16 half4_t __attribute__((ext_vector_type(4)));
typedef _Float16 half8   __attribute__((ext_vector_type(8)));
typedef float    f32x4   __attribute__((ext_vector_type(4)));

#define MFMA16(a, b, c) __builtin_amdgcn_mfma_f32_16x16x32_f16((a), (b), (c), 0, 0, 0)

#define AS1 __attribute__((address_space(1)))
#define AS3 __attribute__((address_space(3)))

__device__ __forceinline__ void gload16(void* lds, const void* g) {
    __builtin_amdgcn_global_load_lds((AS1 void*)(g), (AS3 void*)(lds), 16, 0, 0);
}

// ---- swizzled-LDS access helpers (XOR byte-bits 4..6 with row&7) ----------
__device__ __forceinline__ void at_wr(float* AT, int i, int j, float v) {
    *(float*)((char*)AT + i * 256 + ((j * 4) ^ ((i & 7) << 4))) = v;
}
__device__ __forceinline__ half8 frag64(const half_t* base, int row, int koff) {
    return *(const half8*)((const char*)base + row * 128 + ((koff * 2) ^ ((row & 7) << 4)));
}
__device__ __forceinline__ void w64(half_t* base, int row, int col, float v) {
    *(half_t*)((char*)base + row * 128 + ((col * 2) ^ ((row & 7) << 4))) = (half_t)v;
}
__device__ __forceinline__ half8 frag128(const half_t* base, int row, int koff) {
    return *(const half8*)((const char*)base + row * 256 + ((koff * 2) ^ ((row & 7) << 4)));
}

// ---------------------------------------------------------------------------
// Cast (grid-stride, 2048 blocks)
// ---------------------------------------------------------------------------
__global__ __launch_bounds__(256) void cast_h_k(const float* __restrict__ src,
                                                half_t* __restrict__ dst) {
    const long n4 = (long)8192 * 2048 / 4;
    for (long i = (long)blockIdx.x * 256 + threadIdx.x; i < n4; i += (long)gridDim.x * 256) {
        f32x4 v = *(const f32x4*)(src + i * 4);
        half4_t h;
        h[0] = (half_t)v[0]; h[1] = (half_t)v[1]; h[2] = (half_t)v[2]; h[3] = (half_t)v[3];
        *(half4_t*)(dst + i * 4) = h;
    }
}

// Column-permuted W1T[n][k], n < 12544:
//   [0,2048) q | [2048,4096) k | [4096,8192) v | [8192,8256) ba |
//   [8256,8448) zero pad | [8448,12544) z
__global__ __launch_bounds__(256) void build_w1t_k(const float* __restrict__ Wq,
                                                   const float* __restrict__ Wba,
                                                   half_t* __restrict__ W1T) {
    __shared__ half_t tile[32][33];
    int n0 = blockIdx.x * 32, k0 = blockIdx.y * 32;
    int tx = threadIdx.x & 31, ty = threadIdx.x >> 5;
#pragma unroll
    for (int t = 0; t < 4; ++t) {
        int k = k0 + ty + t * 8, n = n0 + tx;
        float v = 0.f;
        if (n < 2048) {
            int kh = n >> 7, d = n & 127;
            v = Wq[(long)k * 12288 + kh * 768 + d];
        } else if (n < 4096) {
            int n2 = n - 2048; int kh = n2 >> 7, d = n2 & 127;
            v = Wq[(long)k * 12288 + kh * 768 + 128 + d];
        } else if (n < 8192) {
            int n3 = n - 4096; int vh = n3 >> 7, d = n3 & 127;
            int kh = vh >> 1, jj = vh & 1;
            v = Wq[(long)k * 12288 + kh * 768 + 256 + jj * 128 + d];
        } else if (n < 8256) {
            v = Wba[(long)k * 64 + (n - 8192)];
        } else if (n >= 8448) {
            int n4 = n - 8448; int vh = n4 >> 7, d = n4 & 127;
            int kh = vh >> 1, jj = vh & 1;
            v = Wq[(long)k * 12288 + kh * 768 + 512 + jj * 128 + d];
        }
        tile[ty + t * 8][tx] = (half_t)v;
    }
    __syncthreads();
#pragma unroll
    for (int t = 0; t < 4; ++t) {
        int n = n0 + ty + t * 8, k = k0 + tx;
        W1T[(long)n * 2048 + k] = tile[tx][ty + t * 8];
    }
}

// WoT[n][k] = W_out[k][n]; n < 2048, k < 4096
__global__ __launch_bounds__(256) void build_wot_k(const float* __restrict__ Wo,
                                                   half_t* __restrict__ WoT) {
    __shared__ half_t tile[32][33];
    int n0 = blockIdx.x * 32, k0 = blockIdx.y * 32;
    int tx = threadIdx.x & 31, ty = threadIdx.x >> 5;
#pragma unroll
    for (int t = 0; t < 4; ++t) {
        int k = k0 + ty + t * 8, n = n0 + tx;
        tile[ty + t * 8][tx] = (half_t)Wo[(long)k * 2048 + n];
    }
    __syncthreads();
#pragma unroll
    for (int t = 0; t < 4; ++t) {
        int n = n0 + ty + t * 8, k = k0 + tx;
        WoT[(long)n * 4096 + k] = tile[tx][ty + t * 8];
    }
}

// ---------------------------------------------------------------------------
// 256x256 f16 GEMM: C = A(MxK) * Bt(NxK)^T.  1024 threads (16 waves, 4M x 4N,
// 64x64 out/wave), BK=64, LDS 128 KiB (2 dbuf), GROUP_M=8 + XCD swizzle.
// Split output: blocks with tn < tnSplit write C (ldc), others write C2
// (ldc2) at column (tn-tnSplit)*256 — lets two N-ranges share one dispatch
// (B panels contiguous in Bt). Per K-tile iter (2 barriers):
//   kc0: 8 ds_reads + 16 MFMA | kc1: 8 ds_reads + 16 MFMA
//   BAR | stage(kt+2) (4 gloads/thread) | vmcnt(4) retires kt+1 | BAR
// ---------------------------------------------------------------------------
template <int OUT_F16>
__global__ __launch_bounds__(1024, 4) void gemm256_k(const half_t* __restrict__ A,
                                                     const half_t* __restrict__ Bt,
                                                     void* __restrict__ C,
                                                     void* __restrict__ C2,
                                                     int K, int ldc, int ldc2,
                                                     int nwgM, int nwgN, int tnSplit) {
    __shared__ half_t LA[2][2][8192];   // [buf][half][128 rows x 64 f16]
    __shared__ half_t LB[2][2][8192];
    const int tid = threadIdx.x, lane = tid & 63, w = tid >> 6;   // w 0..15
    const int lo = lane & 15, hi = lane >> 4;
    const int wm = w >> 2, wn = w & 3;
    const int nwg = gridDim.x, q = nwg >> 3, bid = blockIdx.x;
    const int swz = (bid & 7) * q + (bid >> 3);
    const int grp = 8 * nwgN;
    const int gid = swz / grp;
    const int rem = swz - gid * grp;
    const int fm = gid * 8;
    const int gsz = min(nwgM - fm, 8);
    const long tm = fm + rem % gsz;
    const long tn = rem / gsz;
    const long Kb = (long)K * 2;
    const char* Ab = (const char*)A + tm * 256 * Kb;
    const char* Bb = (const char*)Bt + tn * 256 * Kb;
    // output select (block-uniform)
    void* Cp;
    long ld, col0;
    if ((int)tn < tnSplit) { Cp = C;  ld = ldc;  col0 = tn * 256; }
    else                   { Cp = C2; ld = ldc2; col0 = (tn - tnSplit) * 256; }
    // staging: wave w writes segs {2w, 2w+1} of 32 x 1KB segs per tile;
    // source column pre-swizzled so swizzled reads see logical data.
    const int scol = ((lane & 7) << 4) ^ ((lane >> 3) << 4);
    const int srow = lane >> 3;
    const int sa0 = w * 2, sa1 = w * 2 + 1;   // seg = h*16 + si

    auto stSeg = [&](half_t (*L)[2][8192], const char* gb0, int kt, int s) {
        int h = s >> 4, si = s & 15;
        gload16((char*)&L[kt & 1][h][0] + si * 1024,
                gb0 + (long)(h * 128 + si * 8 + srow) * Kb + (long)kt * 128 + scol);
    };
    auto stTile = [&](int kt) {
        stSeg(LA, Ab, kt, sa0); stSeg(LA, Ab, kt, sa1);
        stSeg(LB, Bb, kt, sa0); stSeg(LB, Bb, kt, sa1);
    };
    auto rdA = [&](int p, int mt, int kc) -> half8 {
        int r = wm * 64 + mt * 16 + lo;
        int rl = r & 127;
        return *(const half8*)((const char*)&LA[p][r >> 7][0] + rl * 128 +
                               ((kc * 64 + hi * 16) ^ ((rl & 7) << 4)));
    };
    auto rdB = [&](int p, int nt, int kc) -> half8 {
        int r = wn * 64 + nt * 16 + lo;
        int rl = r & 127;
        return *(const half8*)((const char*)&LB[p][r >> 7][0] + rl * 128 +
                               ((kc * 64 + hi * 16) ^ ((rl & 7) << 4)));
    };

    f32x4 acc[4][4] = {};

    const int nkt = K >> 6;
    stTile(0); stTile(1);                                  // 8 outstanding
    asm volatile("s_waitcnt vmcnt(4)" ::: "memory");       // tile 0 landed
    __builtin_amdgcn_s_barrier();

    for (int kt = 0; kt < nkt; ++kt) {
        const int p = kt & 1;
#pragma unroll
        for (int kc = 0; kc < 2; ++kc) {
            half8 af[4], bf[4];
#pragma unroll
            for (int mt = 0; mt < 4; ++mt) af[mt] = rdA(p, mt, kc);
#pragma unroll
            for (int nt = 0; nt < 4; ++nt) bf[nt] = rdB(p, nt, kc);
#pragma unroll
            for (int mt = 0; mt < 4; ++mt)
#pragma unroll
                for (int nt = 0; nt < 4; ++nt)
                    acc[mt][nt] = MFMA16(af[mt], bf[nt], acc[mt][nt]);
        }
        __builtin_amdgcn_s_barrier();      // all buf-p reads done block-wide
        if (kt + 2 < nkt) {
            stTile(kt + 2);                                  // 4 gloads -> buf p
            asm volatile("s_waitcnt vmcnt(4)" ::: "memory"); // kt+1 retired
        } else if (kt + 1 < nkt) {
            asm volatile("s_waitcnt vmcnt(0)" ::: "memory");
        }
        __builtin_amdgcn_s_barrier();      // kt+1 visible block-wide
    }

    const long crow0 = tm * 256 + wm * 64 + hi * 4;
    const long ccol0 = col0 + wn * 64 + lo;
#pragma unroll
    for (int mt = 0; mt < 4; ++mt)
#pragma unroll
        for (int nt = 0; nt < 4; ++nt)
#pragma unroll
            for (int e = 0; e < 4; ++e) {
                long row = crow0 + mt * 16 + e;
                long col = ccol0 + nt * 16;
                if (OUT_F16)
                    ((half_t*)Cp)[row * ld + col] = (half_t)acc[mt][nt][e];
                else
                    ((float*)Cp)[row * ld + col] = acc[mt][nt][e];
            }
}

// ---------------------------------------------------------------------------
// Causal depthwise conv (KW=4) + SiLU + FUSED l2norm (q,k).  8 ch/thread,
// half8 I/O. mixed rows ldm=8448 (cols 0..8191 live). A head's 128 dims =
// 16 consecutive lanes (8 ch each) of one wave -> 4x shfl_xor reduction.
// grid (4, B*128): bx 0=q, 1=k, 2..3=v; 32-s chunks.
// ---------------------------------------------------------------------------
__global__ __launch_bounds__(256) void conv_silu_k(const half_t* __restrict__ mixedH,
                                                   const float* __restrict__ conv_w,
                                                   half_t* __restrict__ qb,
                                                   half_t* __restrict__ kb,
                                                   half_t* __restrict__ vb) {
    const int ldm = 8448;
    int bx = blockIdx.x;
    int ch0 = (bx * 256 + threadIdx.x) * 8;   // 0..8184
    int b = blockIdx.y >> 7, sc = blockIdx.y & 127;
    int s0 = sc * 32;
    half_t* dptr;
    long dstr;
    float nsc = 1.f;
    bool donorm = (bx < 2);
    if (bx == 0)      { dptr = qb + ch0;          dstr = 2048; nsc = 0.08838834764831845f; }
    else if (bx == 1) { dptr = kb + (ch0 - 2048); dstr = 2048; }
    else              { dptr = vb + (ch0 - 4096); dstr = 4096; }
    float w0[8], w1[8], w2[8], w3[8];
#pragma unroll
    for (int j = 0; j < 8; ++j) {
        f32x4 wv = *(const f32x4*)(conv_w + (ch0 + j) * 4);
        w0[j] = wv[0]; w1[j] = wv[1]; w2[j] = wv[2]; w3[j] = wv[3];
    }
    const half_t* src = mixedH + (long)b * 4096 * ldm + ch0;
    half8 x0 = {}, x1 = {}, x2 = {};
    if (s0 >= 3) {
        x0 = *(const half8*)(src + (long)(s0 - 3) * ldm);
        x1 = *(const half8*)(src + (long)(s0 - 2) * ldm);
        x2 = *(const half8*)(src + (long)(s0 - 1) * ldm);
    }
    for (int s = s0; s < s0 + 32; ++s) {
        half8 x3 = *(const half8*)(src + (long)s * ldm);
        float y[8];
        float ss = 0.f;
#pragma unroll
        for (int j = 0; j < 8; ++j) {
            float t = w0[j] * (float)x0[j] + w1[j] * (float)x1[j] +
                      w2[j] * (float)x2[j] + w3[j] * (float)x3[j];
            t = t / (1.f + __expf(-t));
            y[j] = t;
            ss += t * t;
        }
        half8 yv;
        if (donorm) {
            ss += __shfl_xor(ss, 1);
            ss += __shfl_xor(ss, 2);
            ss += __shfl_xor(ss, 4);
            ss += __shfl_xor(ss, 8);
            float r = rsqrtf(ss + 1e-6f) * nsc;
#pragma unroll
            for (int j = 0; j < 8; ++j) yv[j] = (half_t)(y[j] * r);
        } else {
#pragma unroll
            for (int j = 0; j < 8; ++j) yv[j] = (half_t)y[j];
        }
        *(half8*)(dptr + ((long)b * 4096 + s) * dstr) = yv;
        x0 = x1; x1 = x2; x2 = x3;
    }
}

// ---------------------------------------------------------------------------
// beta = sigmoid(b), g = -exp(A_log)*softplus(a+dt_bias), per-chunk cumsum.
// ba at mixedH cols 8192..8255 (row stride 8448).
// ---------------------------------------------------------------------------
__global__ __launch_bounds__(256) void gate_beta_k(const half_t* __restrict__ mixedH,
                                                   const float* __restrict__ A_log,
                                                   const float* __restrict__ dt_bias,
                                                   float* __restrict__ beta,
                                                   float* __restrict__ gcum) {
    __shared__ float gs[32][64];
    int b = blockIdx.x >> 6, c = blockIdx.x & 63;
    for (int idx = threadIdx.x; idx < 2048; idx += 256) {
        int vh = idx & 31, i = idx >> 5;
        int kh = vh >> 1, j = vh & 1;
        long row = ((long)b * 4096 + c * 64 + i) * 8448 + 8192 + kh * 4;
        float bb = (float)mixedH[row + j];
        float aa = (float)mixedH[row + 2 + j];
        beta[((long)b * 4096 + c * 64 + i) * 32 + vh] = 1.f / (1.f + __expf(-bb));
        float x = aa + dt_bias[vh];
        float sp = (x > 15.f) ? x : log1pf(__expf(x));
        gs[vh][i] = -__expf(A_log[vh]) * sp;
    }
    __syncthreads();
    if (threadIdx.x < 32) {
        int vh = threadIdx.x;
        float cum = 0.f;
        float* gout = gcum + ((long)(b * 32 + vh)) * 4096 + c * 64;
        for (int i = 0; i < 64; ++i) { cum += gs[vh][i]; gout[i] = cum; }
    }
}

// ---------------------------------------------------------------------------
// Phase 1: per (b,vh,chunk): A, T=(I-A)^-1, attn, v_t, -kc.  grid 4096.
// ---------------------------------------------------------------------------
__global__ __launch_bounds__(256) void phase1_k(const half_t* __restrict__ qb,
                                                const half_t* __restrict__ kb,
                                                const half_t* __restrict__ vb,
                                                const float* __restrict__ beta,
                                                const float* __restrict__ gcum,
                                                half_t* __restrict__ attnW,
                                                half_t* __restrict__ vtW,
                                                half_t* __restrict__ kcW) {
    __shared__ float AT[64 * 64];       // swizzled rows (256 B); A f32, then T f16
    __shared__ half_t XT[256 * 64];
    __shared__ float gcS[64], betaS[64], egS[64];
    int blk = blockIdx.x;
    int c = blk & 63, vh = (blk >> 6) & 31, b = blk >> 11;
    int kh = vh >> 1;
    int tid = threadIdx.x, lane = tid & 63, w = tid >> 6, lo = lane & 15, hi = lane >> 4;
    long rowbase = (long)b * 4096 + c * 64;
    if (tid < 64) {
        float g = gcum[((long)(b * 32 + vh)) * 4096 + c * 64 + tid];
        gcS[tid] = g; egS[tid] = __expf(g);
        betaS[tid] = beta[(rowbase + tid) * 32 + vh];
    }
    const half_t* kR = kb + rowbase * 2048 + kh * 128;
    const half_t* qR = qb + rowbase * 2048 + kh * 128;
    f32x4 accG[4] = {}, accA[4] = {};
#pragma unroll
    for (int kt = 0; kt < 4; ++kt) {
        half8 ak = *(const half8*)(kR + (long)(w * 16 + lo) * 2048 + kt * 32 + hi * 8);
        half8 aq = *(const half8*)(qR + (long)(w * 16 + lo) * 2048 + kt * 32 + hi * 8);
#pragma unroll
        for (int n = 0; n < 4; ++n) {
            half8 bk = *(const half8*)(kR + (long)(n * 16 + lo) * 2048 + kt * 32 + hi * 8);
            accG[n] = MFMA16(ak, bk, accG[n]);
            accA[n] = MFMA16(aq, bk, accA[n]);
        }
    }
    __syncthreads();
    half_t* attnB = attnW + (long)blk * 4096;
#pragma unroll
    for (int n = 0; n < 4; ++n)
#pragma unroll
        for (int e = 0; e < 4; ++e) {
            int i = w * 16 + hi * 4 + e;
            int j = n * 16 + lo;
            float dec = (j < i) ? __expf(gcS[i] - gcS[j]) : 0.f;
            float av = (j < i) ? (-betaS[i] * accG[n][e] * dec) : (j == i ? 1.f : 0.f);
            at_wr(AT, i, j, av);
            attnB[(long)i * 64 + j] = (half_t)((j < i) ? accA[n][e] * dec : 0.f);
        }
    __syncthreads();
    if (w == 0) {
        float t[64];
#pragma unroll
        for (int i = 0; i < 64; ++i) t[i] = (lane == i) ? 1.f : 0.f;
#pragma unroll
        for (int i = 1; i < 64; ++i) {
            float a0 = 0.f, a1 = 0.f, a2 = 0.f, a3 = 0.f;
#pragma unroll
            for (int p0 = 0; p0 < i; p0 += 4) {
                f32x4 a4 = *(const f32x4*)((const char*)AT + i * 256 +
                                           ((p0 * 4) ^ ((i & 7) << 4)));
                if (p0 + 0 < i) a0 += a4[0] * t[p0 + 0];
                if (p0 + 1 < i) a1 += a4[1] * t[p0 + 1];
                if (p0 + 2 < i) a2 += a4[2] * t[p0 + 2];
                if (p0 + 3 < i) a3 += a4[3] * t[p0 + 3];
            }
            t[i] += (a0 + a1) + (a2 + a3);
        }
        half_t* TS = (half_t*)AT;
#pragma unroll
        for (int i = 0; i < 64; ++i)
            *(half_t*)((char*)TS + i * 128 + ((lane * 2) ^ ((i & 7) << 4))) = (half_t)t[i];
    } else {
        for (int idx = tid - 64; idx < 4096; idx += 192) {
            int p = idx >> 6, dp = idx & 63;
            float bb = betaS[p], be = betaS[p] * egS[p];
            half2_t vv = *(const half2_t*)(vb + (rowbase + p) * 4096 + vh * 128 + dp * 2);
            half2_t kk = *(const half2_t*)(kb + (rowbase + p) * 2048 + kh * 128 + dp * 2);
            w64(XT, dp * 2,       p, (float)vv[0] * bb);
            w64(XT, dp * 2 + 1,   p, (float)vv[1] * bb);
            w64(XT, 128 + dp * 2,     p, (float)kk[0] * be);
            w64(XT, 128 + dp * 2 + 1, p, (float)kk[1] * be);
        }
    }
    __syncthreads();
    const half_t* TS = (const half_t*)AT;
    f32x4 accO[4][4] = {};
#pragma unroll
    for (int kt = 0; kt < 2; ++kt) {
        half8 tf[4];
#pragma unroll
        for (int m = 0; m < 4; ++m) tf[m] = frag64(TS, m * 16 + lo, kt * 32 + hi * 8);
#pragma unroll
        for (int n = 0; n < 4; ++n) {
            half8 bx = frag64(XT, w * 64 + n * 16 + lo, kt * 32 + hi * 8);
#pragma unroll
            for (int m = 0; m < 4; ++m) accO[m][n] = MFMA16(tf[m], bx, accO[m][n]);
        }
    }
    long ob = (long)blk * 8192;
#pragma unroll
    for (int m = 0; m < 4; ++m)
#pragma unroll
        for (int n = 0; n < 4; ++n)
#pragma unroll
            for (int e = 0; e < 4; ++e) {
                int i = m * 16 + hi * 4 + e;
                int dc = w * 64 + n * 16 + lo;
                float v = accO[m][n][e];
                if (dc < 128) vtW[ob + (long)i * 128 + dc] = (half_t)v;
                else          kcW[ob + (long)i * 128 + dc - 128] = (half_t)(-v);
            }
}

// ---------------------------------------------------------------------------
// Phase 2: sequential chunk scan per (b,vh,DV-slice of 32). grid 256.
// ---------------------------------------------------------------------------
struct P2Ops {
    half8 kcf[4], qf[4], k8[4];
    half8 atf[2];
    half_t vtv[8];
    float gm, gi, g63;
};

__global__ __launch_bounds__(256, 1) void phase2_k(const half_t* __restrict__ qb,
                                                   const half_t* __restrict__ kb,
                                                   const float* __restrict__ gcum,
                                                   const half_t* __restrict__ attnW,
                                                   const half_t* __restrict__ vtW,
                                                   const half_t* __restrict__ kcW,
                                                   half_t* __restrict__ coreH) {
    __shared__ half_t SHs[32 * 128];
    __shared__ half_t vnT[32 * 64];
    __shared__ half_t kdT[128 * 64];
    int blk = blockIdx.x;
    int bvh = blk & 63, js = blk >> 6;
    int vh = bvh & 31, b = bvh >> 5, kh = vh >> 1;
    int j0 = js * 32;
    int tid = threadIdx.x, lane = tid & 63, w = tid >> 6, lo = lane & 15, hi = lane >> 4;
    int ii = tid >> 2, dseg = tid & 3;
    int jm = w >> 1, dql = (w & 1) * 4;
    for (int idx = tid; idx < 32 * 128; idx += 256) SHs[idx] = (half_t)0.f;
    __syncthreads();
    const float* gbase = gcum + (long)bvh * 4096;

    auto loadops = [&](int c, P2Ops& o) {
        long pb = (long)bvh * 64 + c;
        const half_t* kcG = kcW + pb * 8192;
        const half_t* vtG = vtW + pb * 8192;
        const half_t* atG = attnW + pb * 4096;
        long rowbase = (long)b * 4096 + c * 64;
        const float* gp = gbase + c * 64;
#pragma unroll
        for (int kt = 0; kt < 4; ++kt) {
            o.kcf[kt] = *(const half8*)(kcG + (long)(w * 16 + lo) * 128 + kt * 32 + hi * 8);
            o.qf[kt] = *(const half8*)(qb + (rowbase + w * 16 + lo) * 2048 + kh * 128 +
                                       kt * 32 + hi * 8);
        }
#pragma unroll
        for (int kt2 = 0; kt2 < 2; ++kt2)
            o.atf[kt2] = *(const half8*)(atG + (long)(w * 16 + lo) * 64 + kt2 * 32 + hi * 8);
#pragma unroll
        for (int s = 0; s < 4; ++s)
            o.k8[s] = *(const half8*)(kb + (rowbase + ii) * 2048 + kh * 128 + dseg * 32 + s * 8);
#pragma unroll
        for (int n = 0; n < 2; ++n)
#pragma unroll
            for (int e = 0; e < 4; ++e)
                o.vtv[n * 4 + e] = vtG[(long)(w * 16 + hi * 4 + e) * 128 + j0 + n * 16 + lo];
        o.gm = gp[w * 16 + lo];
        o.gi = gp[ii];
        o.g63 = gp[63];
    };

    auto step = [&](int c, P2Ops& o, P2Ops& nx) {
        long rowbase = (long)b * 4096 + c * 64;
        loadops(c + 1 < 64 ? c + 1 : 63, nx);
        half8 bS[4][2];
#pragma unroll
        for (int kt = 0; kt < 4; ++kt) {
            bS[kt][0] = frag128(SHs, lo, kt * 32 + hi * 8);
            bS[kt][1] = frag128(SHs, 16 + lo, kt * 32 + hi * 8);
        }
        f32x4 accV[2];
#pragma unroll
        for (int n = 0; n < 2; ++n)
#pragma unroll
            for (int e = 0; e < 4; ++e) accV[n][e] = (float)o.vtv[n * 4 + e];
#pragma unroll
        for (int kt = 0; kt < 4; ++kt) {
            accV[0] = MFMA16(o.kcf[kt], bS[kt][0], accV[0]);
            accV[1] = MFMA16(o.kcf[kt], bS[kt][1], accV[1]);
        }
#pragma unroll
        for (int n = 0; n < 2; ++n) {
            int j = n * 16 + lo, i0 = w * 16 + hi * 4;
            half4_t h4;
            h4[0] = (half_t)accV[n][0]; h4[1] = (half_t)accV[n][1];
            h4[2] = (half_t)accV[n][2]; h4[3] = (half_t)accV[n][3];
            *(half4_t*)((char*)vnT + j * 128 + ((i0 * 2) ^ ((j & 7) << 4))) = h4;
        }
        {
            float ek = __expf(o.g63 - o.gi);
#pragma unroll
            for (int s = 0; s < 4; ++s)
#pragma unroll
                for (int e2 = 0; e2 < 8; ++e2)
                    w64(kdT, dseg * 32 + s * 8 + e2, ii, (float)o.k8[s][e2] * ek);
        }
        __syncthreads();
        float egm = __expf(o.gm);
        f32x4 accO[2] = {};
#pragma unroll
        for (int kt = 0; kt < 4; ++kt) {
            half8 aq;
#pragma unroll
            for (int e2 = 0; e2 < 8; ++e2) aq[e2] = (half_t)((float)o.qf[kt][e2] * egm);
            accO[0] = MFMA16(aq, bS[kt][0], accO[0]);
            accO[1] = MFMA16(aq, bS[kt][1], accO[1]);
        }
#pragma unroll
        for (int kt2 = 0; kt2 < 2; ++kt2) {
            half8 bV0 = frag64(vnT, lo, kt2 * 32 + hi * 8);
            half8 bV1 = frag64(vnT, 16 + lo, kt2 * 32 + hi * 8);
            accO[0] = MFMA16(o.atf[kt2], bV0, accO[0]);
            accO[1] = MFMA16(o.atf[kt2], bV1, accO[1]);
        }
        f32x4 accU[4] = {};
#pragma unroll
        for (int kt2 = 0; kt2 < 2; ++kt2) {
            half8 avn = frag64(vnT, jm * 16 + lo, kt2 * 32 + hi * 8);
#pragma unroll
            for (int dnn = 0; dnn < 4; ++dnn) {
                half8 bkd = frag64(kdT, (dql + dnn) * 16 + lo, kt2 * 32 + hi * 8);
                accU[dnn] = MFMA16(avn, bkd, accU[dnn]);
            }
        }
#pragma unroll
        for (int n = 0; n < 2; ++n)
#pragma unroll
            for (int e = 0; e < 4; ++e)
                coreH[(rowbase + w * 16 + hi * 4 + e) * 4096 + vh * 128 + j0 + n * 16 + lo] =
                    (half_t)accO[n][e];
        __syncthreads();
        float egl = __expf(o.g63);
#pragma unroll
        for (int dnn = 0; dnn < 4; ++dnn)
#pragma unroll
            for (int e = 0; e < 4; ++e) {
                int j = jm * 16 + hi * 4 + e;
                int d = (dql + dnn) * 16 + lo;
                char* p = (char*)SHs + j * 256 + ((d * 2) ^ ((j & 7) << 4));
                float old = (float)*(half_t*)p;
                *(half_t*)p = (half_t)(old * egl + accU[dnn][e]);
            }
        __syncthreads();
    };

    P2Ops opsA, opsB;
    loadops(0, opsA);
    for (int c = 0; c < 64; c += 2) {
        step(c, opsA, opsB);
        step(c + 1, opsB, opsA);
    }
}

// ---------------------------------------------------------------------------
// Gated RMSNorm + silu(z) gate, IN-PLACE on coreH. One wave per (b,s,vh) row.
// Grid-stride: 4096 blocks x 4 waves x 16 iters = 262144 rows.
// ---------------------------------------------------------------------------
__global__ __launch_bounds__(256) void normgate_k(half_t* __restrict__ coreH,
                                                  const half_t* __restrict__ zH,
                                                  const float* __restrict__ norm_w) {
    int w = threadIdx.x >> 6, lane = threadIdx.x & 63;
    float w0 = norm_w[lane * 2], w1 = norm_w[lane * 2 + 1];
    for (long rid = (long)blockIdx.x * 4 + w; rid < 262144; rid += (long)gridDim.x * 4) {
        long bs = rid >> 5;
        int vh = rid & 31;
        half_t* cr = coreH + bs * 4096 + vh * 128;
        half2_t cv = *(half2_t*)(cr + lane * 2);
        float f0 = (float)cv[0], f1 = (float)cv[1];
        float ss = f0 * f0 + f1 * f1;
#pragma unroll
        for (int off = 32; off; off >>= 1) ss += __shfl_xor(ss, off);
        float rs = rsqrtf(ss * (1.f / 128.f) + 1e-6f);
        half2_t zz = *(const half2_t*)(zH + bs * 4096 + vh * 128 + lane * 2);
        float z0 = (float)zz[0], z1 = (float)zz[1];
        float s0 = z0 / (1.f + __expf(-z0)), s1 = z1 / (1.f + __expf(-z1));
        half2_t o;
        o[0] = (half_t)(f0 * rs * w0 * s0);
        o[1] = (half_t)(f1 * rs * w1 * s1);
        *(half2_t*)(cr + lane * 2) = o;
    }
}

// ---------------------------------------------------------------------------
// Host launcher.  Workspace layout (MiB offsets), hand-aliased, peak 370 MiB:
//   [0,32)    qb      | overlay: hiddenH
//   [32,64)   kb      | overlay: W1T head (W1T = 12544x2048 f16, 49 MiB)
//   [64,128)  vb      | overlay: W1T tail; later coreH
//   [128,129) betaB   [129,130) gcum   [130,146) WoT
//   [146,210) zH
//   [210,342) mixedH (8192 x 8448 f16, 132 MiB) | overlay: attnW [210,242),
//                                                  vtW [242,306), kcW [306,370)
// ---------------------------------------------------------------------------
extern "C" void kernel_launch(void* const* d_in, const int* in_sizes, int n_in,
                              void* d_out, int out_size, void* d_ws, size_t ws_size,
                              hipStream_t stream) {
    const float* hidden  = (const float*)d_in[0];
    const float* W_qkvz  = (const float*)d_in[1];
    const float* W_ba    = (const float*)d_in[2];
    const float* conv_w  = (const float*)d_in[3];
    const float* A_log   = (const float*)d_in[4];
    const float* dt_bias = (const float*)d_in[5];
    const float* norm_w  = (const float*)d_in[6];
    const float* W_out   = (const float*)d_in[7];
    float* out = (float*)d_out;

    char* ws = (char*)d_ws;
    const size_t MB = 1ull << 20;
    half_t* qb      = (half_t*)(ws + 0);
    half_t* kb      = (half_t*)(ws + 32 * MB);
    half_t* vb      = (half_t*)(ws + 64 * MB);
    float*  betaB   = (float*) (ws + 128 * MB);
    float*  gcum    = (float*) (ws + 129 * MB);
    half_t* WoT     = (half_t*)(ws + 130 * MB);
    half_t* zH      = (half_t*)(ws + 146 * MB);
    half_t* mixedH  = (half_t*)(ws + 210 * MB);
    half_t* attnW   = (half_t*)(ws + 210 * MB);
    half_t* vtW     = (half_t*)(ws + 242 * MB);
    half_t* kcW     = (half_t*)(ws + 306 * MB);
    half_t* hiddenH = (half_t*)(ws + 0);
    half_t* W1T     = (half_t*)(ws + 32 * MB);
    half_t* coreH   = (half_t*)(ws + 64 * MB);
    (void)ws_size; (void)in_sizes; (void)n_in; (void)out_size;

    // 1. casts / transposes
    cast_h_k<<<2048, 256, 0, stream>>>(hidden, hiddenH);
    build_w1t_k<<<dim3(392, 64), 256, 0, stream>>>(W_qkvz, W_ba, W1T);
    build_wot_k<<<dim3(64, 128), 256, 0, stream>>>(W_out, WoT);
    // 2. fused projection, ONE dispatch: qkv+ba (tn<33 -> mixedH, ldc 8448)
    //    and z (tn>=33 -> zH, ldc 4096); N_total = 12544, K=2048.
    gemm256_k<1><<<1568, 1024, 0, stream>>>(hiddenH, W1T, mixedH, zH,
                                            2048, 8448, 4096, 32, 49, 33);
    // 3. conv + silu + fused l2norm ; gates
    conv_silu_k<<<dim3(4, 256), 256, 0, stream>>>(mixedH, conv_w, qb, kb, vb);
    gate_beta_k<<<128, 256, 0, stream>>>(mixedH, A_log, dt_bias, betaB, gcum);
    // 4. delta-rule core
    phase1_k<<<4096, 256, 0, stream>>>(qb, kb, vb, betaB, gcum, attnW, vtW, kcW);
    phase2_k<<<256, 256, 0, stream>>>(qb, kb, gcum, attnW, vtW, kcW, coreH);
    // 5. gated RMSNorm (in-place) + output projection (M=8192, N=2048, K=4096)
    normgate_k<<<4096, 256, 0, stream>>>(coreH, zH, norm_w);
    gemm256_k<0><<<256, 1024, 0, stream>>>(coreH, WoT, out, nullptr,
                                           4096, 2048, 0, 32, 8, 8);
}

// Round 15
// 1072.082 us; speedup vs baseline: 2.9077x; 1.0175x over previous
//
#include <hip/hip_runtime.h>
#include <cstdint>
#include <cstddef>

// ---------------------------------------------------------------------------
// Qwen3.5 GatedDeltaNet forward, MI355X (gfx950), f16-MFMA implementation.
// B=2, S=4096, H=2048, HK=16, HV=32, DK=DV=128, KW=4, CS=64.
// R2: phase2 split 4x across DV.  R3: phase1 register-resident solve.
// R4/R5: 256x256 GEMM (swizzled LDS, XCD swz, GROUP_M=8 map).
// R8: conv/l2norm fusion + grid-stride smalls.  R9: flattened K-loop.
// R10/R12: 16 waves, 64x64/wave — 1110 us.  R13: merged projection dispatch
//      + setprio removed — 1091 us.
// R14: barrier-early reorder — kc1 MFMA quad moved AFTER the staging
//      barriers (register-only; overlaps stage-issue + next-tile ds_reads).
//      BAR1 now preceded by lgkmcnt(0) in every wave, so buf-p reads are
//      retired block-wide before the overwriting gload_lds (stronger than
//      before). Live-across-barrier = 1 kc fragment set (32 VGPR) — half of
//      R11's spill trigger.
// ---------------------------------------------------------------------------

typedef _Float16 half_t;
typedef _Float16 half2_t __attribute__((ext_vector_type(2)));
typedef _Float16 half4_t __attribute__((ext_vector_type(4)));
typedef _Float16 half8   __attribute__((ext_vector_type(8)));
typedef float    f32x4   __attribute__((ext_vector_type(4)));

#define MFMA16(a, b, c) __builtin_amdgcn_mfma_f32_16x16x32_f16((a), (b), (c), 0, 0, 0)

#define AS1 __attribute__((address_space(1)))
#define AS3 __attribute__((address_space(3)))

__device__ __forceinline__ void gload16(void* lds, const void* g) {
    __builtin_amdgcn_global_load_lds((AS1 void*)(g), (AS3 void*)(lds), 16, 0, 0);
}

// ---- swizzled-LDS access helpers (XOR byte-bits 4..6 with row&7) ----------
__device__ __forceinline__ void at_wr(float* AT, int i, int j, float v) {
    *(float*)((char*)AT + i * 256 + ((j * 4) ^ ((i & 7) << 4))) = v;
}
__device__ __forceinline__ half8 frag64(const half_t* base, int row, int koff) {
    return *(const half8*)((const char*)base + row * 128 + ((koff * 2) ^ ((row & 7) << 4)));
}
__device__ __forceinline__ void w64(half_t* base, int row, int col, float v) {
    *(half_t*)((char*)base + row * 128 + ((col * 2) ^ ((row & 7) << 4))) = (half_t)v;
}
__device__ __forceinline__ half8 frag128(const half_t* base, int row, int koff) {
    return *(const half8*)((const char*)base + row * 256 + ((koff * 2) ^ ((row & 7) << 4)));
}

// ---------------------------------------------------------------------------
// Cast (grid-stride, 2048 blocks)
// ---------------------------------------------------------------------------
__global__ __launch_bounds__(256) void cast_h_k(const float* __restrict__ src,
                                                half_t* __restrict__ dst) {
    const long n4 = (long)8192 * 2048 / 4;
    for (long i = (long)blockIdx.x * 256 + threadIdx.x; i < n4; i += (long)gridDim.x * 256) {
        f32x4 v = *(const f32x4*)(src + i * 4);
        half4_t h;
        h[0] = (half_t)v[0]; h[1] = (half_t)v[1]; h[2] = (half_t)v[2]; h[3] = (half_t)v[3];
        *(half4_t*)(dst + i * 4) = h;
    }
}

// Column-permuted W1T[n][k], n < 12544:
//   [0,2048) q | [2048,4096) k | [4096,8192) v | [8192,8256) ba |
//   [8256,8448) zero pad | [8448,12544) z
__global__ __launch_bounds__(256) void build_w1t_k(const float* __restrict__ Wq,
                                                   const float* __restrict__ Wba,
                                                   half_t* __restrict__ W1T) {
    __shared__ half_t tile[32][33];
    int n0 = blockIdx.x * 32, k0 = blockIdx.y * 32;
    int tx = threadIdx.x & 31, ty = threadIdx.x >> 5;
#pragma unroll
    for (int t = 0; t < 4; ++t) {
        int k = k0 + ty + t * 8, n = n0 + tx;
        float v = 0.f;
        if (n < 2048) {
            int kh = n >> 7, d = n & 127;
            v = Wq[(long)k * 12288 + kh * 768 + d];
        } else if (n < 4096) {
            int n2 = n - 2048; int kh = n2 >> 7, d = n2 & 127;
            v = Wq[(long)k * 12288 + kh * 768 + 128 + d];
        } else if (n < 8192) {
            int n3 = n - 4096; int vh = n3 >> 7, d = n3 & 127;
            int kh = vh >> 1, jj = vh & 1;
            v = Wq[(long)k * 12288 + kh * 768 + 256 + jj * 128 + d];
        } else if (n < 8256) {
            v = Wba[(long)k * 64 + (n - 8192)];
        } else if (n >= 8448) {
            int n4 = n - 8448; int vh = n4 >> 7, d = n4 & 127;
            int kh = vh >> 1, jj = vh & 1;
            v = Wq[(long)k * 12288 + kh * 768 + 512 + jj * 128 + d];
        }
        tile[ty + t * 8][tx] = (half_t)v;
    }
    __syncthreads();
#pragma unroll
    for (int t = 0; t < 4; ++t) {
        int n = n0 + ty + t * 8, k = k0 + tx;
        W1T[(long)n * 2048 + k] = tile[tx][ty + t * 8];
    }
}

// WoT[n][k] = W_out[k][n]; n < 2048, k < 4096
__global__ __launch_bounds__(256) void build_wot_k(const float* __restrict__ Wo,
                                                   half_t* __restrict__ WoT) {
    __shared__ half_t tile[32][33];
    int n0 = blockIdx.x * 32, k0 = blockIdx.y * 32;
    int tx = threadIdx.x & 31, ty = threadIdx.x >> 5;
#pragma unroll
    for (int t = 0; t < 4; ++t) {
        int k = k0 + ty + t * 8, n = n0 + tx;
        tile[ty + t * 8][tx] = (half_t)Wo[(long)k * 2048 + n];
    }
    __syncthreads();
#pragma unroll
    for (int t = 0; t < 4; ++t) {
        int n = n0 + ty + t * 8, k = k0 + tx;
        WoT[(long)n * 4096 + k] = tile[tx][ty + t * 8];
    }
}

// ---------------------------------------------------------------------------
// 256x256 f16 GEMM: C = A(MxK) * Bt(NxK)^T.  1024 threads (16 waves, 4M x 4N,
// 64x64 out/wave), BK=64, LDS 128 KiB (2 dbuf), GROUP_M=8 + XCD swizzle.
// Split output: blocks with tn < tnSplit write C (ldc), others write C2.
// R14 per-K-tile schedule (2 barriers):
//   reads kc0 | MFMA kc0 | reads kc1 | lgkmcnt(0) | BAR1 |
//   stage(kt+2), vmcnt(4) | BAR2 | MFMA kc1 (register-only, overlaps next
//   iter's ds_reads of the other buffer).
// ---------------------------------------------------------------------------
template <int OUT_F16>
__global__ __launch_bounds__(1024, 4) void gemm256_k(const half_t* __restrict__ A,
                                                     const half_t* __restrict__ Bt,
                                                     void* __restrict__ C,
                                                     void* __restrict__ C2,
                                                     int K, int ldc, int ldc2,
                                                     int nwgM, int nwgN, int tnSplit) {
    __shared__ half_t LA[2][2][8192];   // [buf][half][128 rows x 64 f16]
    __shared__ half_t LB[2][2][8192];
    const int tid = threadIdx.x, lane = tid & 63, w = tid >> 6;   // w 0..15
    const int lo = lane & 15, hi = lane >> 4;
    const int wm = w >> 2, wn = w & 3;
    const int nwg = gridDim.x, q = nwg >> 3, bid = blockIdx.x;
    const int swz = (bid & 7) * q + (bid >> 3);
    const int grp = 8 * nwgN;
    const int gid = swz / grp;
    const int rem = swz - gid * grp;
    const int fm = gid * 8;
    const int gsz = min(nwgM - fm, 8);
    const long tm = fm + rem % gsz;
    const long tn = rem / gsz;
    const long Kb = (long)K * 2;
    const char* Ab = (const char*)A + tm * 256 * Kb;
    const char* Bb = (const char*)Bt + tn * 256 * Kb;
    // output select (block-uniform)
    void* Cp;
    long ld, col0;
    if ((int)tn < tnSplit) { Cp = C;  ld = ldc;  col0 = tn * 256; }
    else                   { Cp = C2; ld = ldc2; col0 = (tn - tnSplit) * 256; }
    // staging: wave w writes segs {2w, 2w+1} of 32 x 1KB segs per tile;
    // source column pre-swizzled so swizzled reads see logical data.
    const int scol = ((lane & 7) << 4) ^ ((lane >> 3) << 4);
    const int srow = lane >> 3;
    const int sa0 = w * 2, sa1 = w * 2 + 1;   // seg = h*16 + si

    auto stSeg = [&](half_t (*L)[2][8192], const char* gb0, int kt, int s) {
        int h = s >> 4, si = s & 15;
        gload16((char*)&L[kt & 1][h][0] + si * 1024,
                gb0 + (long)(h * 128 + si * 8 + srow) * Kb + (long)kt * 128 + scol);
    };
    auto stTile = [&](int kt) {
        stSeg(LA, Ab, kt, sa0); stSeg(LA, Ab, kt, sa1);
        stSeg(LB, Bb, kt, sa0); stSeg(LB, Bb, kt, sa1);
    };
    auto rdA = [&](int p, int mt, int kc) -> half8 {
        int r = wm * 64 + mt * 16 + lo;
        int rl = r & 127;
        return *(const half8*)((const char*)&LA[p][r >> 7][0] + rl * 128 +
                               ((kc * 64 + hi * 16) ^ ((rl & 7) << 4)));
    };
    auto rdB = [&](int p, int nt, int kc) -> half8 {
        int r = wn * 64 + nt * 16 + lo;
        int rl = r & 127;
        return *(const half8*)((const char*)&LB[p][r >> 7][0] + rl * 128 +
                               ((kc * 64 + hi * 16) ^ ((rl & 7) << 4)));
    };

    f32x4 acc[4][4] = {};
    half8 af[4], bf[4];

    auto rdFrags = [&](int p, int kc) {
#pragma unroll
        for (int mt = 0; mt < 4; ++mt) af[mt] = rdA(p, mt, kc);
#pragma unroll
        for (int nt = 0; nt < 4; ++nt) bf[nt] = rdB(p, nt, kc);
    };
    auto mfmaQ = [&]() {
#pragma unroll
        for (int mt = 0; mt < 4; ++mt)
#pragma unroll
            for (int nt = 0; nt < 4; ++nt)
                acc[mt][nt] = MFMA16(af[mt], bf[nt], acc[mt][nt]);
    };

    const int nkt = K >> 6;
    stTile(0); stTile(1);                                  // 8 outstanding
    asm volatile("s_waitcnt vmcnt(4)" ::: "memory");       // tile 0 landed
    __builtin_amdgcn_s_barrier();

    for (int kt = 0; kt < nkt; ++kt) {
        const int p = kt & 1;
        rdFrags(p, 0);
        mfmaQ();                                            // kc0
        rdFrags(p, 1);
        asm volatile("s_waitcnt lgkmcnt(0)" ::: "memory");  // buf-p reads retired
        __builtin_amdgcn_s_barrier();                       // ... block-wide
        if (kt + 2 < nkt) {
            stTile(kt + 2);                                  // 4 gloads -> buf p
            asm volatile("s_waitcnt vmcnt(4)" ::: "memory"); // kt+1 retired
        } else if (kt + 1 < nkt) {
            asm volatile("s_waitcnt vmcnt(0)" ::: "memory");
        }
        __builtin_amdgcn_s_barrier();      // kt+1 visible block-wide
        mfmaQ();                           // kc1 (registers; overlaps next reads)
    }

    const long crow0 = tm * 256 + wm * 64 + hi * 4;
    const long ccol0 = col0 + wn * 64 + lo;
#pragma unroll
    for (int mt = 0; mt < 4; ++mt)
#pragma unroll
        for (int nt = 0; nt < 4; ++nt)
#pragma unroll
            for (int e = 0; e < 4; ++e) {
                long row = crow0 + mt * 16 + e;
                long col = ccol0 + nt * 16;
                if (OUT_F16)
                    ((half_t*)Cp)[row * ld + col] = (half_t)acc[mt][nt][e];
                else
                    ((float*)Cp)[row * ld + col] = acc[mt][nt][e];
            }
}

// ---------------------------------------------------------------------------
// Causal depthwise conv (KW=4) + SiLU + FUSED l2norm (q,k).  8 ch/thread,
// half8 I/O. mixed rows ldm=8448 (cols 0..8191 live). A head's 128 dims =
// 16 consecutive lanes (8 ch each) of one wave -> 4x shfl_xor reduction.
// grid (4, B*128): bx 0=q, 1=k, 2..3=v; 32-s chunks.
// ---------------------------------------------------------------------------
__global__ __launch_bounds__(256) void conv_silu_k(const half_t* __restrict__ mixedH,
                                                   const float* __restrict__ conv_w,
                                                   half_t* __restrict__ qb,
                                                   half_t* __restrict__ kb,
                                                   half_t* __restrict__ vb) {
    const int ldm = 8448;
    int bx = blockIdx.x;
    int ch0 = (bx * 256 + threadIdx.x) * 8;   // 0..8184
    int b = blockIdx.y >> 7, sc = blockIdx.y & 127;
    int s0 = sc * 32;
    half_t* dptr;
    long dstr;
    float nsc = 1.f;
    bool donorm = (bx < 2);
    if (bx == 0)      { dptr = qb + ch0;          dstr = 2048; nsc = 0.08838834764831845f; }
    else if (bx == 1) { dptr = kb + (ch0 - 2048); dstr = 2048; }
    else              { dptr = vb + (ch0 - 4096); dstr = 4096; }
    float w0[8], w1[8], w2[8], w3[8];
#pragma unroll
    for (int j = 0; j < 8; ++j) {
        f32x4 wv = *(const f32x4*)(conv_w + (ch0 + j) * 4);
        w0[j] = wv[0]; w1[j] = wv[1]; w2[j] = wv[2]; w3[j] = wv[3];
    }
    const half_t* src = mixedH + (long)b * 4096 * ldm + ch0;
    half8 x0 = {}, x1 = {}, x2 = {};
    if (s0 >= 3) {
        x0 = *(const half8*)(src + (long)(s0 - 3) * ldm);
        x1 = *(const half8*)(src + (long)(s0 - 2) * ldm);
        x2 = *(const half8*)(src + (long)(s0 - 1) * ldm);
    }
    for (int s = s0; s < s0 + 32; ++s) {
        half8 x3 = *(const half8*)(src + (long)s * ldm);
        float y[8];
        float ss = 0.f;
#pragma unroll
        for (int j = 0; j < 8; ++j) {
            float t = w0[j] * (float)x0[j] + w1[j] * (float)x1[j] +
                      w2[j] * (float)x2[j] + w3[j] * (float)x3[j];
            t = t / (1.f + __expf(-t));
            y[j] = t;
            ss += t * t;
        }
        half8 yv;
        if (donorm) {
            ss += __shfl_xor(ss, 1);
            ss += __shfl_xor(ss, 2);
            ss += __shfl_xor(ss, 4);
            ss += __shfl_xor(ss, 8);
            float r = rsqrtf(ss + 1e-6f) * nsc;
#pragma unroll
            for (int j = 0; j < 8; ++j) yv[j] = (half_t)(y[j] * r);
        } else {
#pragma unroll
            for (int j = 0; j < 8; ++j) yv[j] = (half_t)y[j];
        }
        *(half8*)(dptr + ((long)b * 4096 + s) * dstr) = yv;
        x0 = x1; x1 = x2; x2 = x3;
    }
}

// ---------------------------------------------------------------------------
// beta = sigmoid(b), g = -exp(A_log)*softplus(a+dt_bias), per-chunk cumsum.
// ba at mixedH cols 8192..8255 (row stride 8448).
// ---------------------------------------------------------------------------
__global__ __launch_bounds__(256) void gate_beta_k(const half_t* __restrict__ mixedH,
                                                   const float* __restrict__ A_log,
                                                   const float* __restrict__ dt_bias,
                                                   float* __restrict__ beta,
                                                   float* __restrict__ gcum) {
    __shared__ float gs[32][64];
    int b = blockIdx.x >> 6, c = blockIdx.x & 63;
    for (int idx = threadIdx.x; idx < 2048; idx += 256) {
        int vh = idx & 31, i = idx >> 5;
        int kh = vh >> 1, j = vh & 1;
        long row = ((long)b * 4096 + c * 64 + i) * 8448 + 8192 + kh * 4;
        float bb = (float)mixedH[row + j];
        float aa = (float)mixedH[row + 2 + j];
        beta[((long)b * 4096 + c * 64 + i) * 32 + vh] = 1.f / (1.f + __expf(-bb));
        float x = aa + dt_bias[vh];
        float sp = (x > 15.f) ? x : log1pf(__expf(x));
        gs[vh][i] = -__expf(A_log[vh]) * sp;
    }
    __syncthreads();
    if (threadIdx.x < 32) {
        int vh = threadIdx.x;
        float cum = 0.f;
        float* gout = gcum + ((long)(b * 32 + vh)) * 4096 + c * 64;
        for (int i = 0; i < 64; ++i) { cum += gs[vh][i]; gout[i] = cum; }
    }
}

// ---------------------------------------------------------------------------
// Phase 1: per (b,vh,chunk): A, T=(I-A)^-1, attn, v_t, -kc.  grid 4096.
// ---------------------------------------------------------------------------
__global__ __launch_bounds__(256) void phase1_k(const half_t* __restrict__ qb,
                                                const half_t* __restrict__ kb,
                                                const half_t* __restrict__ vb,
                                                const float* __restrict__ beta,
                                                const float* __restrict__ gcum,
                                                half_t* __restrict__ attnW,
                                                half_t* __restrict__ vtW,
                                                half_t* __restrict__ kcW) {
    __shared__ float AT[64 * 64];       // swizzled rows (256 B); A f32, then T f16
    __shared__ half_t XT[256 * 64];
    __shared__ float gcS[64], betaS[64], egS[64];
    int blk = blockIdx.x;
    int c = blk & 63, vh = (blk >> 6) & 31, b = blk >> 11;
    int kh = vh >> 1;
    int tid = threadIdx.x, lane = tid & 63, w = tid >> 6, lo = lane & 15, hi = lane >> 4;
    long rowbase = (long)b * 4096 + c * 64;
    if (tid < 64) {
        float g = gcum[((long)(b * 32 + vh)) * 4096 + c * 64 + tid];
        gcS[tid] = g; egS[tid] = __expf(g);
        betaS[tid] = beta[(rowbase + tid) * 32 + vh];
    }
    const half_t* kR = kb + rowbase * 2048 + kh * 128;
    const half_t* qR = qb + rowbase * 2048 + kh * 128;
    f32x4 accG[4] = {}, accA[4] = {};
#pragma unroll
    for (int kt = 0; kt < 4; ++kt) {
        half8 ak = *(const half8*)(kR + (long)(w * 16 + lo) * 2048 + kt * 32 + hi * 8);
        half8 aq = *(const half8*)(qR + (long)(w * 16 + lo) * 2048 + kt * 32 + hi * 8);
#pragma unroll
        for (int n = 0; n < 4; ++n) {
            half8 bk = *(const half8*)(kR + (long)(n * 16 + lo) * 2048 + kt * 32 + hi * 8);
            accG[n] = MFMA16(ak, bk, accG[n]);
            accA[n] = MFMA16(aq, bk, accA[n]);
        }
    }
    __syncthreads();
    half_t* attnB = attnW + (long)blk * 4096;
#pragma unroll
    for (int n = 0; n < 4; ++n)
#pragma unroll
        for (int e = 0; e < 4; ++e) {
            int i = w * 16 + hi * 4 + e;
            int j = n * 16 + lo;
            float dec = (j < i) ? __expf(gcS[i] - gcS[j]) : 0.f;
            float av = (j < i) ? (-betaS[i] * accG[n][e] * dec) : (j == i ? 1.f : 0.f);
            at_wr(AT, i, j, av);
            attnB[(long)i * 64 + j] = (half_t)((j < i) ? accA[n][e] * dec : 0.f);
        }
    __syncthreads();
    if (w == 0) {
        float t[64];
#pragma unroll
        for (int i = 0; i < 64; ++i) t[i] = (lane == i) ? 1.f : 0.f;
#pragma unroll
        for (int i = 1; i < 64; ++i) {
            float a0 = 0.f, a1 = 0.f, a2 = 0.f, a3 = 0.f;
#pragma unroll
            for (int p0 = 0; p0 < i; p0 += 4) {
                f32x4 a4 = *(const f32x4*)((const char*)AT + i * 256 +
                                           ((p0 * 4) ^ ((i & 7) << 4)));
                if (p0 + 0 < i) a0 += a4[0] * t[p0 + 0];
                if (p0 + 1 < i) a1 += a4[1] * t[p0 + 1];
                if (p0 + 2 < i) a2 += a4[2] * t[p0 + 2];
                if (p0 + 3 < i) a3 += a4[3] * t[p0 + 3];
            }
            t[i] += (a0 + a1) + (a2 + a3);
        }
        half_t* TS = (half_t*)AT;
#pragma unroll
        for (int i = 0; i < 64; ++i)
            *(half_t*)((char*)TS + i * 128 + ((lane * 2) ^ ((i & 7) << 4))) = (half_t)t[i];
    } else {
        for (int idx = tid - 64; idx < 4096; idx += 192) {
            int p = idx >> 6, dp = idx & 63;
            float bb = betaS[p], be = betaS[p] * egS[p];
            half2_t vv = *(const half2_t*)(vb + (rowbase + p) * 4096 + vh * 128 + dp * 2);
            half2_t kk = *(const half2_t*)(kb + (rowbase + p) * 2048 + kh * 128 + dp * 2);
            w64(XT, dp * 2,       p, (float)vv[0] * bb);
            w64(XT, dp * 2 + 1,   p, (float)vv[1] * bb);
            w64(XT, 128 + dp * 2,     p, (float)kk[0] * be);
            w64(XT, 128 + dp * 2 + 1, p, (float)kk[1] * be);
        }
    }
    __syncthreads();
    const half_t* TS = (const half_t*)AT;
    f32x4 accO[4][4] = {};
#pragma unroll
    for (int kt = 0; kt < 2; ++kt) {
        half8 tf[4];
#pragma unroll
        for (int m = 0; m < 4; ++m) tf[m] = frag64(TS, m * 16 + lo, kt * 32 + hi * 8);
#pragma unroll
        for (int n = 0; n < 4; ++n) {
            half8 bx = frag64(XT, w * 64 + n * 16 + lo, kt * 32 + hi * 8);
#pragma unroll
            for (int m = 0; m < 4; ++m) accO[m][n] = MFMA16(tf[m], bx, accO[m][n]);
        }
    }
    long ob = (long)blk * 8192;
#pragma unroll
    for (int m = 0; m < 4; ++m)
#pragma unroll
        for (int n = 0; n < 4; ++n)
#pragma unroll
            for (int e = 0; e < 4; ++e) {
                int i = m * 16 + hi * 4 + e;
                int dc = w * 64 + n * 16 + lo;
                float v = accO[m][n][e];
                if (dc < 128) vtW[ob + (long)i * 128 + dc] = (half_t)v;
                else          kcW[ob + (long)i * 128 + dc - 128] = (half_t)(-v);
            }
}

// ---------------------------------------------------------------------------
// Phase 2: sequential chunk scan per (b,vh,DV-slice of 32). grid 256.
// ---------------------------------------------------------------------------
struct P2Ops {
    half8 kcf[4], qf[4], k8[4];
    half8 atf[2];
    half_t vtv[8];
    float gm, gi, g63;
};

__global__ __launch_bounds__(256, 1) void phase2_k(const half_t* __restrict__ qb,
                                                   const half_t* __restrict__ kb,
                                                   const float* __restrict__ gcum,
                                                   const half_t* __restrict__ attnW,
                                                   const half_t* __restrict__ vtW,
                                                   const half_t* __restrict__ kcW,
                                                   half_t* __restrict__ coreH) {
    __shared__ half_t SHs[32 * 128];
    __shared__ half_t vnT[32 * 64];
    __shared__ half_t kdT[128 * 64];
    int blk = blockIdx.x;
    int bvh = blk & 63, js = blk >> 6;
    int vh = bvh & 31, b = bvh >> 5, kh = vh >> 1;
    int j0 = js * 32;
    int tid = threadIdx.x, lane = tid & 63, w = tid >> 6, lo = lane & 15, hi = lane >> 4;
    int ii = tid >> 2, dseg = tid & 3;
    int jm = w >> 1, dql = (w & 1) * 4;
    for (int idx = tid; idx < 32 * 128; idx += 256) SHs[idx] = (half_t)0.f;
    __syncthreads();
    const float* gbase = gcum + (long)bvh * 4096;

    auto loadops = [&](int c, P2Ops& o) {
        long pb = (long)bvh * 64 + c;
        const half_t* kcG = kcW + pb * 8192;
        const half_t* vtG = vtW + pb * 8192;
        const half_t* atG = attnW + pb * 4096;
        long rowbase = (long)b * 4096 + c * 64;
        const float* gp = gbase + c * 64;
#pragma unroll
        for (int kt = 0; kt < 4; ++kt) {
            o.kcf[kt] = *(const half8*)(kcG + (long)(w * 16 + lo) * 128 + kt * 32 + hi * 8);
            o.qf[kt] = *(const half8*)(qb + (rowbase + w * 16 + lo) * 2048 + kh * 128 +
                                       kt * 32 + hi * 8);
        }
#pragma unroll
        for (int kt2 = 0; kt2 < 2; ++kt2)
            o.atf[kt2] = *(const half8*)(atG + (long)(w * 16 + lo) * 64 + kt2 * 32 + hi * 8);
#pragma unroll
        for (int s = 0; s < 4; ++s)
            o.k8[s] = *(const half8*)(kb + (rowbase + ii) * 2048 + kh * 128 + dseg * 32 + s * 8);
#pragma unroll
        for (int n = 0; n < 2; ++n)
#pragma unroll
            for (int e = 0; e < 4; ++e)
                o.vtv[n * 4 + e] = vtG[(long)(w * 16 + hi * 4 + e) * 128 + j0 + n * 16 + lo];
        o.gm = gp[w * 16 + lo];
        o.gi = gp[ii];
        o.g63 = gp[63];
    };

    auto step = [&](int c, P2Ops& o, P2Ops& nx) {
        long rowbase = (long)b * 4096 + c * 64;
        loadops(c + 1 < 64 ? c + 1 : 63, nx);
        half8 bS[4][2];
#pragma unroll
        for (int kt = 0; kt < 4; ++kt) {
            bS[kt][0] = frag128(SHs, lo, kt * 32 + hi * 8);
            bS[kt][1] = frag128(SHs, 16 + lo, kt * 32 + hi * 8);
        }
        f32x4 accV[2];
#pragma unroll
        for (int n = 0; n < 2; ++n)
#pragma unroll
            for (int e = 0; e < 4; ++e) accV[n][e] = (float)o.vtv[n * 4 + e];
#pragma unroll
        for (int kt = 0; kt < 4; ++kt) {
            accV[0] = MFMA16(o.kcf[kt], bS[kt][0], accV[0]);
            accV[1] = MFMA16(o.kcf[kt], bS[kt][1], accV[1]);
        }
#pragma unroll
        for (int n = 0; n < 2; ++n) {
            int j = n * 16 + lo, i0 = w * 16 + hi * 4;
            half4_t h4;
            h4[0] = (half_t)accV[n][0]; h4[1] = (half_t)accV[n][1];
            h4[2] = (half_t)accV[n][2]; h4[3] = (half_t)accV[n][3];
            *(half4_t*)((char*)vnT + j * 128 + ((i0 * 2) ^ ((j & 7) << 4))) = h4;
        }
        {
            float ek = __expf(o.g63 - o.gi);
#pragma unroll
            for (int s = 0; s < 4; ++s)
#pragma unroll
                for (int e2 = 0; e2 < 8; ++e2)
                    w64(kdT, dseg * 32 + s * 8 + e2, ii, (float)o.k8[s][e2] * ek);
        }
        __syncthreads();
        float egm = __expf(o.gm);
        f32x4 accO[2] = {};
#pragma unroll
        for (int kt = 0; kt < 4; ++kt) {
            half8 aq;
#pragma unroll
            for (int e2 = 0; e2 < 8; ++e2) aq[e2] = (half_t)((float)o.qf[kt][e2] * egm);
            accO[0] = MFMA16(aq, bS[kt][0], accO[0]);
            accO[1] = MFMA16(aq, bS[kt][1], accO[1]);
        }
#pragma unroll
        for (int kt2 = 0; kt2 < 2; ++kt2) {
            half8 bV0 = frag64(vnT, lo, kt2 * 32 + hi * 8);
            half8 bV1 = frag64(vnT, 16 + lo, kt2 * 32 + hi * 8);
            accO[0] = MFMA16(o.atf[kt2], bV0, accO[0]);
            accO[1] = MFMA16(o.atf[kt2], bV1, accO[1]);
        }
        f32x4 accU[4] = {};
#pragma unroll
        for (int kt2 = 0; kt2 < 2; ++kt2) {
            half8 avn = frag64(vnT, jm * 16 + lo, kt2 * 32 + hi * 8);
#pragma unroll
            for (int dnn = 0; dnn < 4; ++dnn) {
                half8 bkd = frag64(kdT, (dql + dnn) * 16 + lo, kt2 * 32 + hi * 8);
                accU[dnn] = MFMA16(avn, bkd, accU[dnn]);
            }
        }
#pragma unroll
        for (int n = 0; n < 2; ++n)
#pragma unroll
            for (int e = 0; e < 4; ++e)
                coreH[(rowbase + w * 16 + hi * 4 + e) * 4096 + vh * 128 + j0 + n * 16 + lo] =
                    (half_t)accO[n][e];
        __syncthreads();
        float egl = __expf(o.g63);
#pragma unroll
        for (int dnn = 0; dnn < 4; ++dnn)
#pragma unroll
            for (int e = 0; e < 4; ++e) {
                int j = jm * 16 + hi * 4 + e;
                int d = (dql + dnn) * 16 + lo;
                char* p = (char*)SHs + j * 256 + ((d * 2) ^ ((j & 7) << 4));
                float old = (float)*(half_t*)p;
                *(half_t*)p = (half_t)(old * egl + accU[dnn][e]);
            }
        __syncthreads();
    };

    P2Ops opsA, opsB;
    loadops(0, opsA);
    for (int c = 0; c < 64; c += 2) {
        step(c, opsA, opsB);
        step(c + 1, opsB, opsA);
    }
}

// ---------------------------------------------------------------------------
// Gated RMSNorm + silu(z) gate, IN-PLACE on coreH. One wave per (b,s,vh) row.
// Grid-stride: 4096 blocks x 4 waves x 16 iters = 262144 rows.
// ---------------------------------------------------------------------------
__global__ __launch_bounds__(256) void normgate_k(half_t* __restrict__ coreH,
                                                  const half_t* __restrict__ zH,
                                                  const float* __restrict__ norm_w) {
    int w = threadIdx.x >> 6, lane = threadIdx.x & 63;
    float w0 = norm_w[lane * 2], w1 = norm_w[lane * 2 + 1];
    for (long rid = (long)blockIdx.x * 4 + w; rid < 262144; rid += (long)gridDim.x * 4) {
        long bs = rid >> 5;
        int vh = rid & 31;
        half_t* cr = coreH + bs * 4096 + vh * 128;
        half2_t cv = *(half2_t*)(cr + lane * 2);
        float f0 = (float)cv[0], f1 = (float)cv[1];
        float ss = f0 * f0 + f1 * f1;
#pragma unroll
        for (int off = 32; off; off >>= 1) ss += __shfl_xor(ss, off);
        float rs = rsqrtf(ss * (1.f / 128.f) + 1e-6f);
        half2_t zz = *(const half2_t*)(zH + bs * 4096 + vh * 128 + lane * 2);
        float z0 = (float)zz[0], z1 = (float)zz[1];
        float s0 = z0 / (1.f + __expf(-z0)), s1 = z1 / (1.f + __expf(-z1));
        half2_t o;
        o[0] = (half_t)(f0 * rs * w0 * s0);
        o[1] = (half_t)(f1 * rs * w1 * s1);
        *(half2_t*)(cr + lane * 2) = o;
    }
}

// ---------------------------------------------------------------------------
// Host launcher.  Workspace layout (MiB offsets), hand-aliased, peak 370 MiB:
//   [0,32)    qb      | overlay: hiddenH
//   [32,64)   kb      | overlay: W1T head (W1T = 12544x2048 f16, 49 MiB)
//   [64,128)  vb      | overlay: W1T tail; later coreH
//   [128,129) betaB   [129,130) gcum   [130,146) WoT
//   [146,210) zH
//   [210,342) mixedH (8192 x 8448 f16, 132 MiB) | overlay: attnW [210,242),
//                                                  vtW [242,306), kcW [306,370)
// ---------------------------------------------------------------------------
extern "C" void kernel_launch(void* const* d_in, const int* in_sizes, int n_in,
                              void* d_out, int out_size, void* d_ws, size_t ws_size,
                              hipStream_t stream) {
    const float* hidden  = (const float*)d_in[0];
    const float* W_qkvz  = (const float*)d_in[1];
    const float* W_ba    = (const float*)d_in[2];
    const float* conv_w  = (const float*)d_in[3];
    const float* A_log   = (const float*)d_in[4];
    const float* dt_bias = (const float*)d_in[5];
    const float* norm_w  = (const float*)d_in[6];
    const float* W_out   = (const float*)d_in[7];
    float* out = (float*)d_out;

    char* ws = (char*)d_ws;
    const size_t MB = 1ull << 20;
    half_t* qb      = (half_t*)(ws + 0);
    half_t* kb      = (half_t*)(ws + 32 * MB);
    half_t* vb      = (half_t*)(ws + 64 * MB);
    float*  betaB   = (float*) (ws + 128 * MB);
    float*  gcum    = (float*) (ws + 129 * MB);
    half_t* WoT     = (half_t*)(ws + 130 * MB);
    half_t* zH      = (half_t*)(ws + 146 * MB);
    half_t* mixedH  = (half_t*)(ws + 210 * MB);
    half_t* attnW   = (half_t*)(ws + 210 * MB);
    half_t* vtW     = (half_t*)(ws + 242 * MB);
    half_t* kcW     = (half_t*)(ws + 306 * MB);
    half_t* hiddenH = (half_t*)(ws + 0);
    half_t* W1T     = (half_t*)(ws + 32 * MB);
    half_t* coreH   = (half_t*)(ws + 64 * MB);
    (void)ws_size; (void)in_sizes; (void)n_in; (void)out_size;

    // 1. casts / transposes
    cast_h_k<<<2048, 256, 0, stream>>>(hidden, hiddenH);
    build_w1t_k<<<dim3(392, 64), 256, 0, stream>>>(W_qkvz, W_ba, W1T);
    build_wot_k<<<dim3(64, 128), 256, 0, stream>>>(W_out, WoT);
    // 2. fused projection, ONE dispatch: qkv+ba (tn<33 -> mixedH, ldc 8448)
    //    and z (tn>=33 -> zH, ldc 4096); N_total = 12544, K=2048.
    gemm256_k<1><<<1568, 1024, 0, stream>>>(hiddenH, W1T, mixedH, zH,
                                            2048, 8448, 4096, 32, 49, 33);
    // 3. conv + silu + fused l2norm ; gates
    conv_silu_k<<<dim3(4, 256), 256, 0, stream>>>(mixedH, conv_w, qb, kb, vb);
    gate_beta_k<<<128, 256, 0, stream>>>(mixedH, A_log, dt_bias, betaB, gcum);
    // 4. delta-rule core
    phase1_k<<<4096, 256, 0, stream>>>(qb, kb, vb, betaB, gcum, attnW, vtW, kcW);
    phase2_k<<<256, 256, 0, stream>>>(qb, kb, gcum, attnW, vtW, kcW, coreH);
    // 5. gated RMSNorm (in-place) + output projection (M=8192, N=2048, K=4096)
    normgate_k<<<4096, 256, 0, stream>>>(coreH, zH, norm_w);
    gemm256_k<0><<<256, 1024, 0, stream>>>(coreH, WoT, out, nullptr,
                                           4096, 2048, 0, 32, 8, 8);
}

// Round 16
// 1061.631 us; speedup vs baseline: 2.9363x; 1.0098x over previous
//
#include <hip/hip_runtime.h>
#include <cstdint>
#include <cstddef>

// ---------------------------------------------------------------------------
// Qwen3.5 GatedDeltaNet forward, MI355X (gfx950), f16-MFMA implementation.
// B=2, S=4096, H=2048, HK=16, HV=32, DK=DV=128, KW=4, CS=64.
// R2: phase2 split 4x across DV.  R3: phase1 register-resident solve.
// R4/R5: 256x256 GEMM (swizzled LDS, XCD swz, GROUP_M=8 map).
// R8: conv/l2norm fusion + grid-stride smalls.  R9: flattened K-loop.
// R10/R12: 16 waves, 64x64/wave.  R13: merged projection dispatch.
// R14: barrier-early reorder (kc1 MFMA after staging barriers) — 1072 us.
// R15: cast_h + build_w1t + build_wot fused into ONE dispatch (independent
//      outputs; overlaps their memory traffic, drops 2 launch boundaries).
// ---------------------------------------------------------------------------

typedef _Float16 half_t;
typedef _Float16 half2_t __attribute__((ext_vector_type(2)));
typedef _Float16 half4_t __attribute__((ext_vector_type(4)));
typedef _Float16 half8   __attribute__((ext_vector_type(8)));
typedef float    f32x4   __attribute__((ext_vector_type(4)));

#define MFMA16(a, b, c) __builtin_amdgcn_mfma_f32_16x16x32_f16((a), (b), (c), 0, 0, 0)

#define AS1 __attribute__((address_space(1)))
#define AS3 __attribute__((address_space(3)))

__device__ __forceinline__ void gload16(void* lds, const void* g) {
    __builtin_amdgcn_global_load_lds((AS1 void*)(g), (AS3 void*)(lds), 16, 0, 0);
}

// ---- swizzled-LDS access helpers (XOR byte-bits 4..6 with row&7) ----------
__device__ __forceinline__ void at_wr(float* AT, int i, int j, float v) {
    *(float*)((char*)AT + i * 256 + ((j * 4) ^ ((i & 7) << 4))) = v;
}
__device__ __forceinline__ half8 frag64(const half_t* base, int row, int koff) {
    return *(const half8*)((const char*)base + row * 128 + ((koff * 2) ^ ((row & 7) << 4)));
}
__device__ __forceinline__ void w64(half_t* base, int row, int col, float v) {
    *(half_t*)((char*)base + row * 128 + ((col * 2) ^ ((row & 7) << 4))) = (half_t)v;
}
__device__ __forceinline__ half8 frag128(const half_t* base, int row, int koff) {
    return *(const half8*)((const char*)base + row * 256 + ((koff * 2) ^ ((row & 7) << 4)));
}

// ---------------------------------------------------------------------------
// Fused prep: block ranges
//   [0,2048)          : cast hidden f32 -> f16 (grid-stride by range size)
//   [2048,27136)      : build W1T (bx = i%392, by = i/392)
//   [27136,35328)     : build WoT (bx = i%64,  by = i/64)
// Column-permuted W1T[n][k], n < 12544:
//   [0,2048) q | [2048,4096) k | [4096,8192) v | [8192,8256) ba |
//   [8256,8448) zero pad | [8448,12544) z
// ---------------------------------------------------------------------------
__global__ __launch_bounds__(256) void prep_k(const float* __restrict__ hidden,
                                              const float* __restrict__ Wq,
                                              const float* __restrict__ Wba,
                                              const float* __restrict__ Wo,
                                              half_t* __restrict__ hiddenH,
                                              half_t* __restrict__ W1T,
                                              half_t* __restrict__ WoT) {
    __shared__ half_t tile[32][33];
    const int bid = blockIdx.x;
    if (bid < 2048) {
        const long n4 = (long)8192 * 2048 / 4;
        for (long i = (long)bid * 256 + threadIdx.x; i < n4; i += (long)2048 * 256) {
            f32x4 v = *(const f32x4*)(hidden + i * 4);
            half4_t h;
            h[0] = (half_t)v[0]; h[1] = (half_t)v[1];
            h[2] = (half_t)v[2]; h[3] = (half_t)v[3];
            *(half4_t*)(hiddenH + i * 4) = h;
        }
        return;
    }
    int tx = threadIdx.x & 31, ty = threadIdx.x >> 5;
    if (bid < 27136) {
        int idx = bid - 2048;
        int n0 = (idx % 392) * 32, k0 = (idx / 392) * 32;
#pragma unroll
        for (int t = 0; t < 4; ++t) {
            int k = k0 + ty + t * 8, n = n0 + tx;
            float v = 0.f;
            if (n < 2048) {
                int kh = n >> 7, d = n & 127;
                v = Wq[(long)k * 12288 + kh * 768 + d];
            } else if (n < 4096) {
                int n2 = n - 2048; int kh = n2 >> 7, d = n2 & 127;
                v = Wq[(long)k * 12288 + kh * 768 + 128 + d];
            } else if (n < 8192) {
                int n3 = n - 4096; int vh = n3 >> 7, d = n3 & 127;
                int kh = vh >> 1, jj = vh & 1;
                v = Wq[(long)k * 12288 + kh * 768 + 256 + jj * 128 + d];
            } else if (n < 8256) {
                v = Wba[(long)k * 64 + (n - 8192)];
            } else if (n >= 8448) {
                int n4 = n - 8448; int vh = n4 >> 7, d = n4 & 127;
                int kh = vh >> 1, jj = vh & 1;
                v = Wq[(long)k * 12288 + kh * 768 + 512 + jj * 128 + d];
            }
            tile[ty + t * 8][tx] = (half_t)v;
        }
        __syncthreads();
#pragma unroll
        for (int t = 0; t < 4; ++t) {
            int n = n0 + ty + t * 8, k = k0 + tx;
            W1T[(long)n * 2048 + k] = tile[tx][ty + t * 8];
        }
        return;
    }
    {
        int idx = bid - 27136;
        int n0 = (idx % 64) * 32, k0 = (idx / 64) * 32;
#pragma unroll
        for (int t = 0; t < 4; ++t) {
            int k = k0 + ty + t * 8, n = n0 + tx;
            tile[ty + t * 8][tx] = (half_t)Wo[(long)k * 2048 + n];
        }
        __syncthreads();
#pragma unroll
        for (int t = 0; t < 4; ++t) {
            int n = n0 + ty + t * 8, k = k0 + tx;
            WoT[(long)n * 4096 + k] = tile[tx][ty + t * 8];
        }
    }
}

// ---------------------------------------------------------------------------
// 256x256 f16 GEMM: C = A(MxK) * Bt(NxK)^T.  1024 threads (16 waves, 4M x 4N,
// 64x64 out/wave), BK=64, LDS 128 KiB (2 dbuf), GROUP_M=8 + XCD swizzle.
// Split output: blocks with tn < tnSplit write C (ldc), others write C2.
// R14 per-K-tile schedule (2 barriers):
//   reads kc0 | MFMA kc0 | reads kc1 | lgkmcnt(0) | BAR1 |
//   stage(kt+2), vmcnt(4) | BAR2 | MFMA kc1 (register-only, overlaps next
//   iter's ds_reads of the other buffer).
// ---------------------------------------------------------------------------
template <int OUT_F16>
__global__ __launch_bounds__(1024, 4) void gemm256_k(const half_t* __restrict__ A,
                                                     const half_t* __restrict__ Bt,
                                                     void* __restrict__ C,
                                                     void* __restrict__ C2,
                                                     int K, int ldc, int ldc2,
                                                     int nwgM, int nwgN, int tnSplit) {
    __shared__ half_t LA[2][2][8192];   // [buf][half][128 rows x 64 f16]
    __shared__ half_t LB[2][2][8192];
    const int tid = threadIdx.x, lane = tid & 63, w = tid >> 6;   // w 0..15
    const int lo = lane & 15, hi = lane >> 4;
    const int wm = w >> 2, wn = w & 3;
    const int nwg = gridDim.x, q = nwg >> 3, bid = blockIdx.x;
    const int swz = (bid & 7) * q + (bid >> 3);
    const int grp = 8 * nwgN;
    const int gid = swz / grp;
    const int rem = swz - gid * grp;
    const int fm = gid * 8;
    const int gsz = min(nwgM - fm, 8);
    const long tm = fm + rem % gsz;
    const long tn = rem / gsz;
    const long Kb = (long)K * 2;
    const char* Ab = (const char*)A + tm * 256 * Kb;
    const char* Bb = (const char*)Bt + tn * 256 * Kb;
    // output select (block-uniform)
    void* Cp;
    long ld, col0;
    if ((int)tn < tnSplit) { Cp = C;  ld = ldc;  col0 = tn * 256; }
    else                   { Cp = C2; ld = ldc2; col0 = (tn - tnSplit) * 256; }
    const int scol = ((lane & 7) << 4) ^ ((lane >> 3) << 4);
    const int srow = lane >> 3;
    const int sa0 = w * 2, sa1 = w * 2 + 1;   // seg = h*16 + si

    auto stSeg = [&](half_t (*L)[2][8192], const char* gb0, int kt, int s) {
        int h = s >> 4, si = s & 15;
        gload16((char*)&L[kt & 1][h][0] + si * 1024,
                gb0 + (long)(h * 128 + si * 8 + srow) * Kb + (long)kt * 128 + scol);
    };
    auto stTile = [&](int kt) {
        stSeg(LA, Ab, kt, sa0); stSeg(LA, Ab, kt, sa1);
        stSeg(LB, Bb, kt, sa0); stSeg(LB, Bb, kt, sa1);
    };
    auto rdA = [&](int p, int mt, int kc) -> half8 {
        int r = wm * 64 + mt * 16 + lo;
        int rl = r & 127;
        return *(const half8*)((const char*)&LA[p][r >> 7][0] + rl * 128 +
                               ((kc * 64 + hi * 16) ^ ((rl & 7) << 4)));
    };
    auto rdB = [&](int p, int nt, int kc) -> half8 {
        int r = wn * 64 + nt * 16 + lo;
        int rl = r & 127;
        return *(const half8*)((const char*)&LB[p][r >> 7][0] + rl * 128 +
                               ((kc * 64 + hi * 16) ^ ((rl & 7) << 4)));
    };

    f32x4 acc[4][4] = {};
    half8 af[4], bf[4];

    auto rdFrags = [&](int p, int kc) {
#pragma unroll
        for (int mt = 0; mt < 4; ++mt) af[mt] = rdA(p, mt, kc);
#pragma unroll
        for (int nt = 0; nt < 4; ++nt) bf[nt] = rdB(p, nt, kc);
    };
    auto mfmaQ = [&]() {
#pragma unroll
        for (int mt = 0; mt < 4; ++mt)
#pragma unroll
            for (int nt = 0; nt < 4; ++nt)
                acc[mt][nt] = MFMA16(af[mt], bf[nt], acc[mt][nt]);
    };

    const int nkt = K >> 6;
    stTile(0); stTile(1);                                  // 8 outstanding
    asm volatile("s_waitcnt vmcnt(4)" ::: "memory");       // tile 0 landed
    __builtin_amdgcn_s_barrier();

    for (int kt = 0; kt < nkt; ++kt) {
        const int p = kt & 1;
        rdFrags(p, 0);
        mfmaQ();                                            // kc0
        rdFrags(p, 1);
        asm volatile("s_waitcnt lgkmcnt(0)" ::: "memory");  // buf-p reads retired
        __builtin_amdgcn_s_barrier();                       // ... block-wide
        if (kt + 2 < nkt) {
            stTile(kt + 2);                                  // 4 gloads -> buf p
            asm volatile("s_waitcnt vmcnt(4)" ::: "memory"); // kt+1 retired
        } else if (kt + 1 < nkt) {
            asm volatile("s_waitcnt vmcnt(0)" ::: "memory");
        }
        __builtin_amdgcn_s_barrier();      // kt+1 visible block-wide
        mfmaQ();                           // kc1 (registers; overlaps next reads)
    }

    const long crow0 = tm * 256 + wm * 64 + hi * 4;
    const long ccol0 = col0 + wn * 64 + lo;
#pragma unroll
    for (int mt = 0; mt < 4; ++mt)
#pragma unroll
        for (int nt = 0; nt < 4; ++nt)
#pragma unroll
            for (int e = 0; e < 4; ++e) {
                long row = crow0 + mt * 16 + e;
                long col = ccol0 + nt * 16;
                if (OUT_F16)
                    ((half_t*)Cp)[row * ld + col] = (half_t)acc[mt][nt][e];
                else
                    ((float*)Cp)[row * ld + col] = acc[mt][nt][e];
            }
}

// ---------------------------------------------------------------------------
// Causal depthwise conv (KW=4) + SiLU + FUSED l2norm (q,k).  8 ch/thread,
// half8 I/O. mixed rows ldm=8448 (cols 0..8191 live). A head's 128 dims =
// 16 consecutive lanes (8 ch each) of one wave -> 4x shfl_xor reduction.
// grid (4, B*128): bx 0=q, 1=k, 2..3=v; 32-s chunks.
// ---------------------------------------------------------------------------
__global__ __launch_bounds__(256) void conv_silu_k(const half_t* __restrict__ mixedH,
                                                   const float* __restrict__ conv_w,
                                                   half_t* __restrict__ qb,
                                                   half_t* __restrict__ kb,
                                                   half_t* __restrict__ vb) {
    const int ldm = 8448;
    int bx = blockIdx.x;
    int ch0 = (bx * 256 + threadIdx.x) * 8;   // 0..8184
    int b = blockIdx.y >> 7, sc = blockIdx.y & 127;
    int s0 = sc * 32;
    half_t* dptr;
    long dstr;
    float nsc = 1.f;
    bool donorm = (bx < 2);
    if (bx == 0)      { dptr = qb + ch0;          dstr = 2048; nsc = 0.08838834764831845f; }
    else if (bx == 1) { dptr = kb + (ch0 - 2048); dstr = 2048; }
    else              { dptr = vb + (ch0 - 4096); dstr = 4096; }
    float w0[8], w1[8], w2[8], w3[8];
#pragma unroll
    for (int j = 0; j < 8; ++j) {
        f32x4 wv = *(const f32x4*)(conv_w + (ch0 + j) * 4);
        w0[j] = wv[0]; w1[j] = wv[1]; w2[j] = wv[2]; w3[j] = wv[3];
    }
    const half_t* src = mixedH + (long)b * 4096 * ldm + ch0;
    half8 x0 = {}, x1 = {}, x2 = {};
    if (s0 >= 3) {
        x0 = *(const half8*)(src + (long)(s0 - 3) * ldm);
        x1 = *(const half8*)(src + (long)(s0 - 2) * ldm);
        x2 = *(const half8*)(src + (long)(s0 - 1) * ldm);
    }
    for (int s = s0; s < s0 + 32; ++s) {
        half8 x3 = *(const half8*)(src + (long)s * ldm);
        float y[8];
        float ss = 0.f;
#pragma unroll
        for (int j = 0; j < 8; ++j) {
            float t = w0[j] * (float)x0[j] + w1[j] * (float)x1[j] +
                      w2[j] * (float)x2[j] + w3[j] * (float)x3[j];
            t = t / (1.f + __expf(-t));
            y[j] = t;
            ss += t * t;
        }
        half8 yv;
        if (donorm) {
            ss += __shfl_xor(ss, 1);
            ss += __shfl_xor(ss, 2);
            ss += __shfl_xor(ss, 4);
            ss += __shfl_xor(ss, 8);
            float r = rsqrtf(ss + 1e-6f) * nsc;
#pragma unroll
            for (int j = 0; j < 8; ++j) yv[j] = (half_t)(y[j] * r);
        } else {
#pragma unroll
            for (int j = 0; j < 8; ++j) yv[j] = (half_t)y[j];
        }
        *(half8*)(dptr + ((long)b * 4096 + s) * dstr) = yv;
        x0 = x1; x1 = x2; x2 = x3;
    }
}

// ---------------------------------------------------------------------------
// beta = sigmoid(b), g = -exp(A_log)*softplus(a+dt_bias), per-chunk cumsum.
// ba at mixedH cols 8192..8255 (row stride 8448).
// ---------------------------------------------------------------------------
__global__ __launch_bounds__(256) void gate_beta_k(const half_t* __restrict__ mixedH,
                                                   const float* __restrict__ A_log,
                                                   const float* __restrict__ dt_bias,
                                                   float* __restrict__ beta,
                                                   float* __restrict__ gcum) {
    __shared__ float gs[32][64];
    int b = blockIdx.x >> 6, c = blockIdx.x & 63;
    for (int idx = threadIdx.x; idx < 2048; idx += 256) {
        int vh = idx & 31, i = idx >> 5;
        int kh = vh >> 1, j = vh & 1;
        long row = ((long)b * 4096 + c * 64 + i) * 8448 + 8192 + kh * 4;
        float bb = (float)mixedH[row + j];
        float aa = (float)mixedH[row + 2 + j];
        beta[((long)b * 4096 + c * 64 + i) * 32 + vh] = 1.f / (1.f + __expf(-bb));
        float x = aa + dt_bias[vh];
        float sp = (x > 15.f) ? x : log1pf(__expf(x));
        gs[vh][i] = -__expf(A_log[vh]) * sp;
    }
    __syncthreads();
    if (threadIdx.x < 32) {
        int vh = threadIdx.x;
        float cum = 0.f;
        float* gout = gcum + ((long)(b * 32 + vh)) * 4096 + c * 64;
        for (int i = 0; i < 64; ++i) { cum += gs[vh][i]; gout[i] = cum; }
    }
}

// ---------------------------------------------------------------------------
// Phase 1: per (b,vh,chunk): A, T=(I-A)^-1, attn, v_t, -kc.  grid 4096.
// ---------------------------------------------------------------------------
__global__ __launch_bounds__(256) void phase1_k(const half_t* __restrict__ qb,
                                                const half_t* __restrict__ kb,
                                                const half_t* __restrict__ vb,
                                                const float* __restrict__ beta,
                                                const float* __restrict__ gcum,
                                                half_t* __restrict__ attnW,
                                                half_t* __restrict__ vtW,
                                                half_t* __restrict__ kcW) {
    __shared__ float AT[64 * 64];       // swizzled rows (256 B); A f32, then T f16
    __shared__ half_t XT[256 * 64];
    __shared__ float gcS[64], betaS[64], egS[64];
    int blk = blockIdx.x;
    int c = blk & 63, vh = (blk >> 6) & 31, b = blk >> 11;
    int kh = vh >> 1;
    int tid = threadIdx.x, lane = tid & 63, w = tid >> 6, lo = lane & 15, hi = lane >> 4;
    long rowbase = (long)b * 4096 + c * 64;
    if (tid < 64) {
        float g = gcum[((long)(b * 32 + vh)) * 4096 + c * 64 + tid];
        gcS[tid] = g; egS[tid] = __expf(g);
        betaS[tid] = beta[(rowbase + tid) * 32 + vh];
    }
    const half_t* kR = kb + rowbase * 2048 + kh * 128;
    const half_t* qR = qb + rowbase * 2048 + kh * 128;
    f32x4 accG[4] = {}, accA[4] = {};
#pragma unroll
    for (int kt = 0; kt < 4; ++kt) {
        half8 ak = *(const half8*)(kR + (long)(w * 16 + lo) * 2048 + kt * 32 + hi * 8);
        half8 aq = *(const half8*)(qR + (long)(w * 16 + lo) * 2048 + kt * 32 + hi * 8);
#pragma unroll
        for (int n = 0; n < 4; ++n) {
            half8 bk = *(const half8*)(kR + (long)(n * 16 + lo) * 2048 + kt * 32 + hi * 8);
            accG[n] = MFMA16(ak, bk, accG[n]);
            accA[n] = MFMA16(aq, bk, accA[n]);
        }
    }
    __syncthreads();
    half_t* attnB = attnW + (long)blk * 4096;
#pragma unroll
    for (int n = 0; n < 4; ++n)
#pragma unroll
        for (int e = 0; e < 4; ++e) {
            int i = w * 16 + hi * 4 + e;
            int j = n * 16 + lo;
            float dec = (j < i) ? __expf(gcS[i] - gcS[j]) : 0.f;
            float av = (j < i) ? (-betaS[i] * accG[n][e] * dec) : (j == i ? 1.f : 0.f);
            at_wr(AT, i, j, av);
            attnB[(long)i * 64 + j] = (half_t)((j < i) ? accA[n][e] * dec : 0.f);
        }
    __syncthreads();
    if (w == 0) {
        float t[64];
#pragma unroll
        for (int i = 0; i < 64; ++i) t[i] = (lane == i) ? 1.f : 0.f;
#pragma unroll
        for (int i = 1; i < 64; ++i) {
            float a0 = 0.f, a1 = 0.f, a2 = 0.f, a3 = 0.f;
#pragma unroll
            for (int p0 = 0; p0 < i; p0 += 4) {
                f32x4 a4 = *(const f32x4*)((const char*)AT + i * 256 +
                                           ((p0 * 4) ^ ((i & 7) << 4)));
                if (p0 + 0 < i) a0 += a4[0] * t[p0 + 0];
                if (p0 + 1 < i) a1 += a4[1] * t[p0 + 1];
                if (p0 + 2 < i) a2 += a4[2] * t[p0 + 2];
                if (p0 + 3 < i) a3 += a4[3] * t[p0 + 3];
            }
            t[i] += (a0 + a1) + (a2 + a3);
        }
        half_t* TS = (half_t*)AT;
#pragma unroll
        for (int i = 0; i < 64; ++i)
            *(half_t*)((char*)TS + i * 128 + ((lane * 2) ^ ((i & 7) << 4))) = (half_t)t[i];
    } else {
        for (int idx = tid - 64; idx < 4096; idx += 192) {
            int p = idx >> 6, dp = idx & 63;
            float bb = betaS[p], be = betaS[p] * egS[p];
            half2_t vv = *(const half2_t*)(vb + (rowbase + p) * 4096 + vh * 128 + dp * 2);
            half2_t kk = *(const half2_t*)(kb + (rowbase + p) * 2048 + kh * 128 + dp * 2);
            w64(XT, dp * 2,       p, (float)vv[0] * bb);
            w64(XT, dp * 2 + 1,   p, (float)vv[1] * bb);
            w64(XT, 128 + dp * 2,     p, (float)kk[0] * be);
            w64(XT, 128 + dp * 2 + 1, p, (float)kk[1] * be);
        }
    }
    __syncthreads();
    const half_t* TS = (const half_t*)AT;
    f32x4 accO[4][4] = {};
#pragma unroll
    for (int kt = 0; kt < 2; ++kt) {
        half8 tf[4];
#pragma unroll
        for (int m = 0; m < 4; ++m) tf[m] = frag64(TS, m * 16 + lo, kt * 32 + hi * 8);
#pragma unroll
        for (int n = 0; n < 4; ++n) {
            half8 bx = frag64(XT, w * 64 + n * 16 + lo, kt * 32 + hi * 8);
#pragma unroll
            for (int m = 0; m < 4; ++m) accO[m][n] = MFMA16(tf[m], bx, accO[m][n]);
        }
    }
    long ob = (long)blk * 8192;
#pragma unroll
    for (int m = 0; m < 4; ++m)
#pragma unroll
        for (int n = 0; n < 4; ++n)
#pragma unroll
            for (int e = 0; e < 4; ++e) {
                int i = m * 16 + hi * 4 + e;
                int dc = w * 64 + n * 16 + lo;
                float v = accO[m][n][e];
                if (dc < 128) vtW[ob + (long)i * 128 + dc] = (half_t)v;
                else          kcW[ob + (long)i * 128 + dc - 128] = (half_t)(-v);
            }
}

// ---------------------------------------------------------------------------
// Phase 2: sequential chunk scan per (b,vh,DV-slice of 32). grid 256.
// ---------------------------------------------------------------------------
struct P2Ops {
    half8 kcf[4], qf[4], k8[4];
    half8 atf[2];
    half_t vtv[8];
    float gm, gi, g63;
};

__global__ __launch_bounds__(256, 1) void phase2_k(const half_t* __restrict__ qb,
                                                   const half_t* __restrict__ kb,
                                                   const float* __restrict__ gcum,
                                                   const half_t* __restrict__ attnW,
                                                   const half_t* __restrict__ vtW,
                                                   const half_t* __restrict__ kcW,
                                                   half_t* __restrict__ coreH) {
    __shared__ half_t SHs[32 * 128];
    __shared__ half_t vnT[32 * 64];
    __shared__ half_t kdT[128 * 64];
    int blk = blockIdx.x;
    int bvh = blk & 63, js = blk >> 6;
    int vh = bvh & 31, b = bvh >> 5, kh = vh >> 1;
    int j0 = js * 32;
    int tid = threadIdx.x, lane = tid & 63, w = tid >> 6, lo = lane & 15, hi = lane >> 4;
    int ii = tid >> 2, dseg = tid & 3;
    int jm = w >> 1, dql = (w & 1) * 4;
    for (int idx = tid; idx < 32 * 128; idx += 256) SHs[idx] = (half_t)0.f;
    __syncthreads();
    const float* gbase = gcum + (long)bvh * 4096;

    auto loadops = [&](int c, P2Ops& o) {
        long pb = (long)bvh * 64 + c;
        const half_t* kcG = kcW + pb * 8192;
        const half_t* vtG = vtW + pb * 8192;
        const half_t* atG = attnW + pb * 4096;
        long rowbase = (long)b * 4096 + c * 64;
        const float* gp = gbase + c * 64;
#pragma unroll
        for (int kt = 0; kt < 4; ++kt) {
            o.kcf[kt] = *(const half8*)(kcG + (long)(w * 16 + lo) * 128 + kt * 32 + hi * 8);
            o.qf[kt] = *(const half8*)(qb + (rowbase + w * 16 + lo) * 2048 + kh * 128 +
                                       kt * 32 + hi * 8);
        }
#pragma unroll
        for (int kt2 = 0; kt2 < 2; ++kt2)
            o.atf[kt2] = *(const half8*)(atG + (long)(w * 16 + lo) * 64 + kt2 * 32 + hi * 8);
#pragma unroll
        for (int s = 0; s < 4; ++s)
            o.k8[s] = *(const half8*)(kb + (rowbase + ii) * 2048 + kh * 128 + dseg * 32 + s * 8);
#pragma unroll
        for (int n = 0; n < 2; ++n)
#pragma unroll
            for (int e = 0; e < 4; ++e)
                o.vtv[n * 4 + e] = vtG[(long)(w * 16 + hi * 4 + e) * 128 + j0 + n * 16 + lo];
        o.gm = gp[w * 16 + lo];
        o.gi = gp[ii];
        o.g63 = gp[63];
    };

    auto step = [&](int c, P2Ops& o, P2Ops& nx) {
        long rowbase = (long)b * 4096 + c * 64;
        loadops(c + 1 < 64 ? c + 1 : 63, nx);
        half8 bS[4][2];
#pragma unroll
        for (int kt = 0; kt < 4; ++kt) {
            bS[kt][0] = frag128(SHs, lo, kt * 32 + hi * 8);
            bS[kt][1] = frag128(SHs, 16 + lo, kt * 32 + hi * 8);
        }
        f32x4 accV[2];
#pragma unroll
        for (int n = 0; n < 2; ++n)
#pragma unroll
            for (int e = 0; e < 4; ++e) accV[n][e] = (float)o.vtv[n * 4 + e];
#pragma unroll
        for (int kt = 0; kt < 4; ++kt) {
            accV[0] = MFMA16(o.kcf[kt], bS[kt][0], accV[0]);
            accV[1] = MFMA16(o.kcf[kt], bS[kt][1], accV[1]);
        }
#pragma unroll
        for (int n = 0; n < 2; ++n) {
            int j = n * 16 + lo, i0 = w * 16 + hi * 4;
            half4_t h4;
            h4[0] = (half_t)accV[n][0]; h4[1] = (half_t)accV[n][1];
            h4[2] = (half_t)accV[n][2]; h4[3] = (half_t)accV[n][3];
            *(half4_t*)((char*)vnT + j * 128 + ((i0 * 2) ^ ((j & 7) << 4))) = h4;
        }
        {
            float ek = __expf(o.g63 - o.gi);
#pragma unroll
            for (int s = 0; s < 4; ++s)
#pragma unroll
                for (int e2 = 0; e2 < 8; ++e2)
                    w64(kdT, dseg * 32 + s * 8 + e2, ii, (float)o.k8[s][e2] * ek);
        }
        __syncthreads();
        float egm = __expf(o.gm);
        f32x4 accO[2] = {};
#pragma unroll
        for (int kt = 0; kt < 4; ++kt) {
            half8 aq;
#pragma unroll
            for (int e2 = 0; e2 < 8; ++e2) aq[e2] = (half_t)((float)o.qf[kt][e2] * egm);
            accO[0] = MFMA16(aq, bS[kt][0], accO[0]);
            accO[1] = MFMA16(aq, bS[kt][1], accO[1]);
        }
#pragma unroll
        for (int kt2 = 0; kt2 < 2; ++kt2) {
            half8 bV0 = frag64(vnT, lo, kt2 * 32 + hi * 8);
            half8 bV1 = frag64(vnT, 16 + lo, kt2 * 32 + hi * 8);
            accO[0] = MFMA16(o.atf[kt2], bV0, accO[0]);
            accO[1] = MFMA16(o.atf[kt2], bV1, accO[1]);
        }
        f32x4 accU[4] = {};
#pragma unroll
        for (int kt2 = 0; kt2 < 2; ++kt2) {
            half8 avn = frag64(vnT, jm * 16 + lo, kt2 * 32 + hi * 8);
#pragma unroll
            for (int dnn = 0; dnn < 4; ++dnn) {
                half8 bkd = frag64(kdT, (dql + dnn) * 16 + lo, kt2 * 32 + hi * 8);
                accU[dnn] = MFMA16(avn, bkd, accU[dnn]);
            }
        }
#pragma unroll
        for (int n = 0; n < 2; ++n)
#pragma unroll
            for (int e = 0; e < 4; ++e)
                coreH[(rowbase + w * 16 + hi * 4 + e) * 4096 + vh * 128 + j0 + n * 16 + lo] =
                    (half_t)accO[n][e];
        __syncthreads();
        float egl = __expf(o.g63);
#pragma unroll
        for (int dnn = 0; dnn < 4; ++dnn)
#pragma unroll
            for (int e = 0; e < 4; ++e) {
                int j = jm * 16 + hi * 4 + e;
                int d = (dql + dnn) * 16 + lo;
                char* p = (char*)SHs + j * 256 + ((d * 2) ^ ((j & 7) << 4));
                float old = (float)*(half_t*)p;
                *(half_t*)p = (half_t)(old * egl + accU[dnn][e]);
            }
        __syncthreads();
    };

    P2Ops opsA, opsB;
    loadops(0, opsA);
    for (int c = 0; c < 64; c += 2) {
        step(c, opsA, opsB);
        step(c + 1, opsB, opsA);
    }
}

// ---------------------------------------------------------------------------
// Gated RMSNorm + silu(z) gate, IN-PLACE on coreH. One wave per (b,s,vh) row.
// Grid-stride: 4096 blocks x 4 waves x 16 iters = 262144 rows.
// ---------------------------------------------------------------------------
__global__ __launch_bounds__(256) void normgate_k(half_t* __restrict__ coreH,
                                                  const half_t* __restrict__ zH,
                                                  const float* __restrict__ norm_w) {
    int w = threadIdx.x >> 6, lane = threadIdx.x & 63;
    float w0 = norm_w[lane * 2], w1 = norm_w[lane * 2 + 1];
    for (long rid = (long)blockIdx.x * 4 + w; rid < 262144; rid += (long)gridDim.x * 4) {
        long bs = rid >> 5;
        int vh = rid & 31;
        half_t* cr = coreH + bs * 4096 + vh * 128;
        half2_t cv = *(half2_t*)(cr + lane * 2);
        float f0 = (float)cv[0], f1 = (float)cv[1];
        float ss = f0 * f0 + f1 * f1;
#pragma unroll
        for (int off = 32; off; off >>= 1) ss += __shfl_xor(ss, off);
        float rs = rsqrtf(ss * (1.f / 128.f) + 1e-6f);
        half2_t zz = *(const half2_t*)(zH + bs * 4096 + vh * 128 + lane * 2);
        float z0 = (float)zz[0], z1 = (float)zz[1];
        float s0 = z0 / (1.f + __expf(-z0)), s1 = z1 / (1.f + __expf(-z1));
        half2_t o;
        o[0] = (half_t)(f0 * rs * w0 * s0);
        o[1] = (half_t)(f1 * rs * w1 * s1);
        *(half2_t*)(cr + lane * 2) = o;
    }
}

// ---------------------------------------------------------------------------
// Host launcher.  Workspace layout (MiB offsets), hand-aliased, peak 370 MiB:
//   [0,32)    qb      | overlay: hiddenH
//   [32,64)   kb      | overlay: W1T head (W1T = 12544x2048 f16, 49 MiB)
//   [64,128)  vb      | overlay: W1T tail; later coreH
//   [128,129) betaB   [129,130) gcum   [130,146) WoT
//   [146,210) zH
//   [210,342) mixedH (8192 x 8448 f16, 132 MiB) | overlay: attnW [210,242),
//                                                  vtW [242,306), kcW [306,370)
// ---------------------------------------------------------------------------
extern "C" void kernel_launch(void* const* d_in, const int* in_sizes, int n_in,
                              void* d_out, int out_size, void* d_ws, size_t ws_size,
                              hipStream_t stream) {
    const float* hidden  = (const float*)d_in[0];
    const float* W_qkvz  = (const float*)d_in[1];
    const float* W_ba    = (const float*)d_in[2];
    const float* conv_w  = (const float*)d_in[3];
    const float* A_log   = (const float*)d_in[4];
    const float* dt_bias = (const float*)d_in[5];
    const float* norm_w  = (const float*)d_in[6];
    const float* W_out   = (const float*)d_in[7];
    float* out = (float*)d_out;

    char* ws = (char*)d_ws;
    const size_t MB = 1ull << 20;
    half_t* qb      = (half_t*)(ws + 0);
    half_t* kb      = (half_t*)(ws + 32 * MB);
    half_t* vb      = (half_t*)(ws + 64 * MB);
    float*  betaB   = (float*) (ws + 128 * MB);
    float*  gcum    = (float*) (ws + 129 * MB);
    half_t* WoT     = (half_t*)(ws + 130 * MB);
    half_t* zH      = (half_t*)(ws + 146 * MB);
    half_t* mixedH  = (half_t*)(ws + 210 * MB);
    half_t* attnW   = (half_t*)(ws + 210 * MB);
    half_t* vtW     = (half_t*)(ws + 242 * MB);
    half_t* kcW     = (half_t*)(ws + 306 * MB);
    half_t* hiddenH = (half_t*)(ws + 0);
    half_t* W1T     = (half_t*)(ws + 32 * MB);
    half_t* coreH   = (half_t*)(ws + 64 * MB);
    (void)ws_size; (void)in_sizes; (void)n_in; (void)out_size;

    // 1. fused prep: cast + W1T + WoT (independent outputs, one dispatch)
    prep_k<<<35328, 256, 0, stream>>>(hidden, W_qkvz, W_ba, W_out,
                                      hiddenH, W1T, WoT);
    // 2. fused projection, ONE dispatch: qkv+ba (tn<33 -> mixedH, ldc 8448)
    //    and z (tn>=33 -> zH, ldc 4096); N_total = 12544, K=2048.
    gemm256_k<1><<<1568, 1024, 0, stream>>>(hiddenH, W1T, mixedH, zH,
                                            2048, 8448, 4096, 32, 49, 33);
    // 3. conv + silu + fused l2norm ; gates
    conv_silu_k<<<dim3(4, 256), 256, 0, stream>>>(mixedH, conv_w, qb, kb, vb);
    gate_beta_k<<<128, 256, 0, stream>>>(mixedH, A_log, dt_bias, betaB, gcum);
    // 4. delta-rule core
    phase1_k<<<4096, 256, 0, stream>>>(qb, kb, vb, betaB, gcum, attnW, vtW, kcW);
    phase2_k<<<256, 256, 0, stream>>>(qb, kb, gcum, attnW, vtW, kcW, coreH);
    // 5. gated RMSNorm (in-place) + output projection (M=8192, N=2048, K=4096)
    normgate_k<<<4096, 256, 0, stream>>>(coreH, zH, norm_w);
    gemm256_k<0><<<256, 1024, 0, stream>>>(coreH, WoT, out, nullptr,
                                           4096, 2048, 0, 32, 8, 8);
}